// Round 1
// baseline (1562.460 us; speedup 1.0000x reference)
//
#include <hip/hip_runtime.h>
#include <stdint.h>

typedef unsigned short u16;
typedef unsigned int u32;

#define DEVFN __device__ __forceinline__

constexpr int CB = 4;
constexpr int CT = 2048;
constexpr int CD = 1024;
constexpr int CH = 8;
constexpr int CDK = 128;
constexpr int CDV = 256;
constexpr long NROW = (long)CB * CT;   // 8192

DEVFN float b2f(u16 s){ return __uint_as_float(((u32)s) << 16); }
DEVFN u16 f2b(float f){
  u32 u = __float_as_uint(f);
  u32 r = (u + 0x7fffu + ((u >> 16) & 1u)) >> 16;
  return (u16)r;
}
DEVFN float sigm(float x){ return 1.f / (1.f + expf(-x)); }

// ---------------- cast X to bf16 ----------------
__global__ void cast_f32_bf16_k(const float* __restrict__ in, u16* __restrict__ out, long n4){
  long i = (long)blockIdx.x * blockDim.x + threadIdx.x;
  long stride = (long)gridDim.x * blockDim.x;
  for (; i < n4; i += stride){
    float4 v = ((const float4*)in)[i];
    ushort4 r;
    r.x = f2b(v.x); r.y = f2b(v.y); r.z = f2b(v.z); r.w = f2b(v.w);
    ((ushort4*)out)[i] = r;
  }
}

// ---------------- transpose + cast weights: W (K x N) f32 -> Wt (N x K) bf16 ----------------
__global__ __launch_bounds__(256) void transpose_cast_k(const float* __restrict__ W, u16* __restrict__ Wt, int K, int N){
  __shared__ float tile[32][33];
  int n0 = blockIdx.x * 32, k0 = blockIdx.y * 32;
  int tx = threadIdx.x & 31, ty = threadIdx.x >> 5;   // 32 x 8
  #pragma unroll
  for (int i = 0; i < 4; i++)
    tile[ty + 8*i][tx] = W[(long)(k0 + ty + 8*i) * N + n0 + tx];
  __syncthreads();
  #pragma unroll
  for (int i = 0; i < 4; i++){
    int nn = ty + 8*i;
    Wt[(long)(n0 + nn) * K + k0 + tx] = f2b(tile[tx][nn]);
  }
}

// ---------------- bf16 MFMA GEMM (NT): C[M,N] = A[M,K] * Bt[N,K]^T ----------------
typedef __bf16 bf16x8 __attribute__((ext_vector_type(8)));
typedef float f32x4 __attribute__((ext_vector_type(4)));

DEVFN void store_c(float* p, float v){ *p = v; }
DEVFN void store_c(u16* p, float v){ *p = f2b(v); }

DEVFN void gload16(const void* g, void* l){
  __builtin_amdgcn_global_load_lds((__attribute__((address_space(1))) void*)g,
                                   (__attribute__((address_space(3))) void*)l, 16, 0, 0);
}

template <typename OutT>
__global__ __launch_bounds__(256) void gemm_nt(
    const u16* __restrict__ A, const u16* __restrict__ Bt, OutT* __restrict__ C,
    int M, int N, int K)
{
  __shared__ u16 As[128 * 64];
  __shared__ u16 Bs[128 * 64];
  int tid = threadIdx.x;
  int w = tid >> 6, l = tid & 63;
  int wr = w >> 1, wc = w & 1;
  int m0 = blockIdx.y * 128, n0 = blockIdx.x * 128;

  f32x4 acc[4][4] = {};

  int chr = l >> 3;            // row within 8-row chunk
  int ckc = (l & 7) * 8;       // k element offset within 64
  const u16* Ab = A + (long)m0 * K;
  const u16* Bb = Bt + (long)n0 * K;
  int lr = l & 15, lk = (l >> 4) * 8;

  for (int k0 = 0; k0 < K; k0 += 64){
    #pragma unroll
    for (int i = 0; i < 4; i++){
      int chunk = w * 4 + i;
      int r = chunk * 8 + chr;
      gload16(Ab + (long)r * K + k0 + ckc, &As[chunk * 512 + l * 8]);
      gload16(Bb + (long)r * K + k0 + ckc, &Bs[chunk * 512 + l * 8]);
    }
    __syncthreads();
    #pragma unroll
    for (int kk = 0; kk < 64; kk += 32){
      bf16x8 av[4], bv[4];
      #pragma unroll
      for (int m = 0; m < 4; m++) av[m] = *(const bf16x8*)&As[(wr*64 + m*16 + lr)*64 + kk + lk];
      #pragma unroll
      for (int n = 0; n < 4; n++) bv[n] = *(const bf16x8*)&Bs[(wc*64 + n*16 + lr)*64 + kk + lk];
      #pragma unroll
      for (int m = 0; m < 4; m++)
        #pragma unroll
        for (int n = 0; n < 4; n++)
          acc[m][n] = __builtin_amdgcn_mfma_f32_16x16x32_bf16(av[m], bv[n], acc[m][n], 0, 0, 0);
    }
    __syncthreads();
  }

  int lg = l >> 4;
  #pragma unroll
  for (int m = 0; m < 4; m++)
    #pragma unroll
    for (int n = 0; n < 4; n++)
      #pragma unroll
      for (int j = 0; j < 4; j++){
        long row = m0 + wr*64 + m*16 + lg*4 + j;
        long col = n0 + wc*64 + n*16 + lr;
        store_c(&C[row * (long)N + col], acc[m][n][j]);
      }
}

// ---------------- GEMV for alpha/beta gates ----------------
__global__ __launch_bounds__(256) void gemv_ab_k(
    const float* __restrict__ X, const float* __restrict__ Wa, const float* __restrict__ Wb,
    const float* __restrict__ A_log, const float* __restrict__ dt_bias,
    float* __restrict__ alpha, float* __restrict__ beta)
{
  __shared__ float xs[CD];
  int row = blockIdx.x;
  int tid = threadIdx.x;
  ((float4*)xs)[tid] = ((const float4*)(X + (long)row * CD))[tid];
  __syncthreads();
  int g = tid >> 4, sL = tid & 15;
  int col = g & 7;
  const float* W = (g >= 8) ? Wb : Wa;
  float acc = 0.f;
  for (int k = sL; k < CD; k += 16) acc = fmaf(xs[k], W[k * 8 + col], acc);
  acc += __shfl_xor(acc, 1); acc += __shfl_xor(acc, 2);
  acc += __shfl_xor(acc, 4); acc += __shfl_xor(acc, 8);
  if (sL == 0){
    if (g < 8){
      float xv = acc + dt_bias[col];
      float sp = fmaxf(xv, 0.f) + log1pf(expf(-fabsf(xv)));
      alpha[(long)row * 8 + col] = expf(-expf(A_log[col]) * sp);
    } else {
      beta[(long)row * 8 + col] = sigm(acc);
    }
  }
}

// ---------------- causal depthwise conv + SiLU (+ head L2 norm) ----------------
template<int DH, bool NORM>
__global__ __launch_bounds__(DH) void conv_silu_k(
    const u16* __restrict__ pre, const float* __restrict__ cw, const float* __restrict__ cb,
    u16* __restrict__ out)
{
  int idx = blockIdx.x;
  int h = idx & 7;
  int t = (idx >> 3) & (CT - 1);
  int b = idx >> 14;
  int tidx = threadIdx.x;
  int ch = h * DH + tidx;
  const int C = CH * DH;
  long base = ((long)b * CT + t) * C + ch;
  float acc = cb[ch];
  #pragma unroll
  for (int j = 0; j < 4; j++){
    int tt = t - 3 + j;
    float x = (tt >= 0) ? b2f(pre[base + ((long)j - 3) * C]) : 0.f;
    acc = fmaf(cw[ch * 4 + j], x, acc);
  }
  float y = acc * sigm(acc);
  if (NORM){
    float ss = y * y;
    #pragma unroll
    for (int off = 1; off < 64; off <<= 1) ss += __shfl_xor(ss, off);
    __shared__ float wsum[DH / 64];
    if ((tidx & 63) == 0) wsum[tidx >> 6] = ss;
    __syncthreads();
    float tot = 0.f;
    #pragma unroll
    for (int i = 0; i < DH / 64; i++) tot += wsum[i];
    y *= 1.f / fmaxf(sqrtf(tot), 1e-12f);
  }
  out[base] = f2b(y);
}

// ---------------- sequential delta-rule scan, v-split across blocks ----------------
__global__ __launch_bounds__(256) void scan_kernel(
    const u16* __restrict__ qn, const u16* __restrict__ kn, const u16* __restrict__ vn,
    const float* __restrict__ alpha, const float* __restrict__ beta,
    const float* __restrict__ prev, float* __restrict__ obuf, float* __restrict__ fstate)
{
  constexpr int COLS = 32, CHUNK = 8;
  int blk = blockIdx.x;
  int vs = blk & 7;
  int h = (blk >> 3) & 7;
  int b = blk >> 6;
  int vbase = vs * COLS;
  int tid = threadIdx.x;
  int c = tid & 31;     // column within COLS
  int kq = tid >> 5;    // k-slice 0..7 (16 k's each); also reused as step id for staging
  int w = tid >> 6;     // wave 0..3

  __shared__ float qs[CHUNK][CDK], ks[CHUNK][CDK], vsh[CHUNK][COLS], abv[CHUNK][2];
  __shared__ float pol[2][4][COLS], pkv[2][4][COLS], osb[CHUNK][COLS];

  float s[16];
  {
    const float* pb = prev + ((long)(b * CH + h) * CDK + kq * 16) * CDV + vbase + c;
    #pragma unroll
    for (int i = 0; i < 16; i++) s[i] = pb[(long)i * CDV];
  }

  ushort4 rq, rk, rv; float ra = 0.f, rb = 0.f;
  auto load_chunk = [&](int t0){
    long rowb = ((long)b * CT + t0 + kq) * CH + h;
    rq = ((const ushort4*)(qn + rowb * CDK))[c];
    rk = ((const ushort4*)(kn + rowb * CDK))[c];
    if (c < 8) rv = ((const ushort4*)(vn + rowb * CDV + vbase))[c];
    if (c == 16) ra = alpha[rowb];
    if (c == 17) rb = beta[rowb];
  };
  auto store_chunk = [&](){
    *(float4*)&qs[kq][c * 4] = make_float4(b2f(rq.x), b2f(rq.y), b2f(rq.z), b2f(rq.w));
    *(float4*)&ks[kq][c * 4] = make_float4(b2f(rk.x), b2f(rk.y), b2f(rk.z), b2f(rk.w));
    if (c < 8) *(float4*)&vsh[kq][c * 4] = make_float4(b2f(rv.x), b2f(rv.y), b2f(rv.z), b2f(rv.w));
    if (c == 16) abv[kq][0] = ra;
    if (c == 17) abv[kq][1] = rb;
  };

  load_chunk(0);
  const int NCH = CT / CHUNK;
  for (int chn = 0; chn < NCH; ++chn){
    store_chunk();
    __syncthreads();
    if (chn + 1 < NCH) load_chunk((chn + 1) * CHUNK);

    for (int st = 0; st < CHUNK; ++st){
      int par = st & 1;
      float qf[16], kf[16];
      #pragma unroll
      for (int i = 0; i < 4; i++){
        *(float4*)&qf[i * 4] = *(const float4*)&qs[st][kq * 16 + i * 4];
        *(float4*)&kf[i * 4] = *(const float4*)&ks[st][kq * 16 + i * 4];
      }
      float a0=0,a1=0,a2=0,a3=0,b0=0,b1=0,b2=0,b3=0;
      #pragma unroll
      for (int i = 0; i < 4; i++){
        a0 = fmaf(qf[i],      s[i],      a0);
        a1 = fmaf(qf[4 + i],  s[4 + i],  a1);
        a2 = fmaf(qf[8 + i],  s[8 + i],  a2);
        a3 = fmaf(qf[12 + i], s[12 + i], a3);
        b0 = fmaf(kf[i],      s[i],      b0);
        b1 = fmaf(kf[4 + i],  s[4 + i],  b1);
        b2 = fmaf(kf[8 + i],  s[8 + i],  b2);
        b3 = fmaf(kf[12 + i], s[12 + i], b3);
      }
      float po = (a0 + a1) + (a2 + a3);
      float pk = (b0 + b1) + (b2 + b3);
      po += __shfl_xor(po, 32);
      pk += __shfl_xor(pk, 32);
      if ((tid & 32) == 0){ pol[par][w][c] = po; pkv[par][w][c] = pk; }
      __syncthreads();
      float oc = (pol[par][0][c] + pol[par][1][c]) + (pol[par][2][c] + pol[par][3][c]);
      float kv = (pkv[par][0][c] + pkv[par][1][c]) + (pkv[par][2][c] + pkv[par][3][c]);
      float al = abv[st][0], be = abv[st][1];
      float bd = be * (vsh[st][c] - kv);
      #pragma unroll
      for (int i = 0; i < 16; i++) s[i] = fmaf(al, s[i], bd * kf[i]);
      if (tid < 32) osb[st][c] = oc;
    }
    __syncthreads();
    {
      long rowb = ((long)b * CT + chn * CHUNK + kq) * CH + h;
      obuf[rowb * CDV + vbase + c] = osb[kq][c];
    }
  }
  float* fb = fstate + ((long)(b * CH + h) * CDK + kq * 16) * CDV + vbase + c;
  #pragma unroll
  for (int i = 0; i < 16; i++) fb[(long)i * CDV] = s[i];
}

// ---------------- gated RMSNorm: one wave per (b,t,h) ----------------
__global__ __launch_bounds__(256) void rms_gate_k(
    const float* __restrict__ o, const u16* __restrict__ gate,
    const float* __restrict__ nw, u16* __restrict__ ofin)
{
  long idx = (long)blockIdx.x * 4 + (threadIdx.x >> 6);
  int lane = threadIdx.x & 63;
  long base = idx * CDV + lane * 4;
  float4 ov = *(const float4*)(o + base);
  float ss = ov.x*ov.x + ov.y*ov.y + ov.z*ov.z + ov.w*ov.w;
  #pragma unroll
  for (int off = 1; off < 64; off <<= 1) ss += __shfl_xor(ss, off);
  float r = rsqrtf(ss * (1.f / CDV) + 1e-5f);
  ushort4 g4 = *(const ushort4*)(gate + base);
  float w0 = nw[lane*4], w1 = nw[lane*4+1], w2 = nw[lane*4+2], w3 = nw[lane*4+3];
  ushort4 res;
  res.x = f2b(ov.x * r * w0 * sigm(b2f(g4.x)));
  res.y = f2b(ov.y * r * w1 * sigm(b2f(g4.y)));
  res.z = f2b(ov.z * r * w2 * sigm(b2f(g4.z)));
  res.w = f2b(ov.w * r * w3 * sigm(b2f(g4.w)));
  *(ushort4*)(ofin + base) = res;
}

// ---------------- host launch ----------------
extern "C" void kernel_launch(void* const* d_in, const int* in_sizes, int n_in,
                              void* d_out, int out_size, void* d_ws, size_t ws_size,
                              hipStream_t stream)
{
  (void)in_sizes; (void)n_in; (void)out_size; (void)ws_size;
  const float* X    = (const float*)d_in[0];
  const float* prev = (const float*)d_in[1];
  const float* Wq   = (const float*)d_in[2];
  const float* Wk   = (const float*)d_in[3];
  const float* Wv   = (const float*)d_in[4];
  const float* Wa   = (const float*)d_in[5];
  const float* Wb   = (const float*)d_in[6];
  const float* Wg   = (const float*)d_in[7];
  const float* Wo   = (const float*)d_in[8];
  const float* qcw  = (const float*)d_in[9];
  const float* qcb  = (const float*)d_in[10];
  const float* kcw  = (const float*)d_in[11];
  const float* kcb  = (const float*)d_in[12];
  const float* vcw  = (const float*)d_in[13];
  const float* vcb  = (const float*)d_in[14];
  const float* onw  = (const float*)d_in[15];
  const float* Alog = (const float*)d_in[16];
  const float* dtb  = (const float*)d_in[17];

  float* out = (float*)d_out;
  float* fstate = out + (long)CB * CT * CD;

  char* ws = (char*)d_ws;
  size_t off = 0;
  auto alloc = [&](size_t bytes) -> char* {
    char* p = ws + off;
    off += (bytes + 255) & ~(size_t)255;
    return p;
  };
  u16* Xb   = (u16*)alloc(NROW * CD * 2);
  u16* Wqt  = (u16*)alloc((size_t)1024 * 1024 * 2);
  u16* Wkt  = (u16*)alloc((size_t)1024 * 1024 * 2);
  u16* Wvt  = (u16*)alloc((size_t)2048 * 1024 * 2);
  u16* Wgt  = (u16*)alloc((size_t)2048 * 1024 * 2);
  u16* Wot  = (u16*)alloc((size_t)1024 * 2048 * 2);
  u16* qpre = (u16*)alloc(NROW * 1024 * 2);
  u16* kpre = (u16*)alloc(NROW * 1024 * 2);
  u16* vpre = (u16*)alloc(NROW * 2048 * 2);
  u16* gpre = (u16*)alloc(NROW * 2048 * 2);
  float* alpha = (float*)alloc(NROW * 8 * 4);
  float* beta  = (float*)alloc(NROW * 8 * 4);
  u16* qn   = (u16*)alloc(NROW * 1024 * 2);
  u16* kn   = (u16*)alloc(NROW * 1024 * 2);
  u16* vn   = (u16*)alloc(NROW * 2048 * 2);
  u16* ofin = (u16*)alloc(NROW * 2048 * 2);
  // o (B,T,H,DV) f32 = 67MB reuses the dead qpre+kpre+vpre region (exactly 67MB)
  float* obuf = (float*)qpre;

  cast_f32_bf16_k<<<2048, 256, 0, stream>>>(X, Xb, NROW * CD / 4);
  transpose_cast_k<<<dim3(32, 32), 256, 0, stream>>>(Wq, Wqt, 1024, 1024);
  transpose_cast_k<<<dim3(32, 32), 256, 0, stream>>>(Wk, Wkt, 1024, 1024);
  transpose_cast_k<<<dim3(64, 32), 256, 0, stream>>>(Wv, Wvt, 1024, 2048);
  transpose_cast_k<<<dim3(64, 32), 256, 0, stream>>>(Wg, Wgt, 1024, 2048);
  transpose_cast_k<<<dim3(32, 64), 256, 0, stream>>>(Wo, Wot, 2048, 1024);

  gemm_nt<u16><<<dim3(8, 64), 256, 0, stream>>>(Xb, Wqt, qpre, 8192, 1024, 1024);
  gemm_nt<u16><<<dim3(8, 64), 256, 0, stream>>>(Xb, Wkt, kpre, 8192, 1024, 1024);
  gemm_nt<u16><<<dim3(16, 64), 256, 0, stream>>>(Xb, Wvt, vpre, 8192, 2048, 1024);
  gemm_nt<u16><<<dim3(16, 64), 256, 0, stream>>>(Xb, Wgt, gpre, 8192, 2048, 1024);
  gemv_ab_k<<<8192, 256, 0, stream>>>(X, Wa, Wb, Alog, dtb, alpha, beta);

  conv_silu_k<128, true><<<CB * CT * CH, 128, 0, stream>>>(qpre, qcw, qcb, qn);
  conv_silu_k<128, true><<<CB * CT * CH, 128, 0, stream>>>(kpre, kcw, kcb, kn);
  conv_silu_k<256, false><<<CB * CT * CH, 256, 0, stream>>>(vpre, vcw, vcb, vn);

  scan_kernel<<<CB * CH * 8, 256, 0, stream>>>(qn, kn, vn, alpha, beta, prev, obuf, fstate);

  rms_gate_k<<<CB * CT * CH / 4, 256, 0, stream>>>(obuf, gpre, onw, ofin);
  gemm_nt<float><<<dim3(8, 64), 256, 0, stream>>>(ofin, Wot, out, 8192, 1024, 2048);
}

// Round 2
// 1352.500 us; speedup vs baseline: 1.1552x; 1.1552x over previous
//
#include <hip/hip_runtime.h>
#include <stdint.h>

typedef unsigned short u16;
typedef unsigned int u32;

#define DEVFN __device__ __forceinline__

constexpr int CB = 4;
constexpr int CT = 2048;
constexpr int CD = 1024;
constexpr int CH = 8;
constexpr int CDK = 128;
constexpr int CDV = 256;
constexpr long NROW = (long)CB * CT;   // 8192

DEVFN float b2f(u16 s){ return __uint_as_float(((u32)s) << 16); }
DEVFN u16 f2b(float f){
  u32 u = __float_as_uint(f);
  u32 r = (u + 0x7fffu + ((u >> 16) & 1u)) >> 16;
  return (u16)r;
}
DEVFN float sigm(float x){ return 1.f / (1.f + expf(-x)); }

// ---------------- cast X to bf16 ----------------
__global__ void cast_f32_bf16_k(const float* __restrict__ in, u16* __restrict__ out, long n4){
  long i = (long)blockIdx.x * blockDim.x + threadIdx.x;
  long stride = (long)gridDim.x * blockDim.x;
  for (; i < n4; i += stride){
    float4 v = ((const float4*)in)[i];
    ushort4 r;
    r.x = f2b(v.x); r.y = f2b(v.y); r.z = f2b(v.z); r.w = f2b(v.w);
    ((ushort4*)out)[i] = r;
  }
}

// ---------------- transpose + cast weights: W (K x N) f32 -> Wt (N x K) bf16 ----------------
__global__ __launch_bounds__(256) void transpose_cast_k(const float* __restrict__ W, u16* __restrict__ Wt, int K, int N){
  __shared__ float tile[32][33];
  int n0 = blockIdx.x * 32, k0 = blockIdx.y * 32;
  int tx = threadIdx.x & 31, ty = threadIdx.x >> 5;   // 32 x 8
  #pragma unroll
  for (int i = 0; i < 4; i++)
    tile[ty + 8*i][tx] = W[(long)(k0 + ty + 8*i) * N + n0 + tx];
  __syncthreads();
  #pragma unroll
  for (int i = 0; i < 4; i++){
    int nn = ty + 8*i;
    Wt[(long)(n0 + nn) * K + k0 + tx] = f2b(tile[tx][nn]);
  }
}

// ---------------- bf16 MFMA GEMM (NT): C[M,N] = A[M,K] * Bt[N,K]^T ----------------
typedef __bf16 bf16x8 __attribute__((ext_vector_type(8)));
typedef float f32x4 __attribute__((ext_vector_type(4)));

DEVFN void store_c(float* p, float v){ *p = v; }
DEVFN void store_c(u16* p, float v){ *p = f2b(v); }

DEVFN void gload16(const void* g, void* l){
  __builtin_amdgcn_global_load_lds((__attribute__((address_space(1))) void*)g,
                                   (__attribute__((address_space(3))) void*)l, 16, 0, 0);
}

template <typename OutT>
__global__ __launch_bounds__(256) void gemm_nt(
    const u16* __restrict__ A, const u16* __restrict__ Bt, OutT* __restrict__ C,
    int M, int N, int K)
{
  __shared__ u16 As[128 * 64];
  __shared__ u16 Bs[128 * 64];
  int tid = threadIdx.x;
  int w = tid >> 6, l = tid & 63;
  int wr = w >> 1, wc = w & 1;
  int m0 = blockIdx.y * 128, n0 = blockIdx.x * 128;

  f32x4 acc[4][4] = {};

  int chr = l >> 3;            // row within 8-row chunk
  int ckc = (l & 7) * 8;       // k element offset within 64
  const u16* Ab = A + (long)m0 * K;
  const u16* Bb = Bt + (long)n0 * K;
  int lr = l & 15, lk = (l >> 4) * 8;

  for (int k0 = 0; k0 < K; k0 += 64){
    #pragma unroll
    for (int i = 0; i < 4; i++){
      int chunk = w * 4 + i;
      int r = chunk * 8 + chr;
      gload16(Ab + (long)r * K + k0 + ckc, &As[chunk * 512 + l * 8]);
      gload16(Bb + (long)r * K + k0 + ckc, &Bs[chunk * 512 + l * 8]);
    }
    __syncthreads();
    #pragma unroll
    for (int kk = 0; kk < 64; kk += 32){
      bf16x8 av[4], bv[4];
      #pragma unroll
      for (int m = 0; m < 4; m++) av[m] = *(const bf16x8*)&As[(wr*64 + m*16 + lr)*64 + kk + lk];
      #pragma unroll
      for (int n = 0; n < 4; n++) bv[n] = *(const bf16x8*)&Bs[(wc*64 + n*16 + lr)*64 + kk + lk];
      #pragma unroll
      for (int m = 0; m < 4; m++)
        #pragma unroll
        for (int n = 0; n < 4; n++)
          acc[m][n] = __builtin_amdgcn_mfma_f32_16x16x32_bf16(av[m], bv[n], acc[m][n], 0, 0, 0);
    }
    __syncthreads();
  }

  int lg = l >> 4;
  #pragma unroll
  for (int m = 0; m < 4; m++)
    #pragma unroll
    for (int n = 0; n < 4; n++)
      #pragma unroll
      for (int j = 0; j < 4; j++){
        long row = m0 + wr*64 + m*16 + lg*4 + j;
        long col = n0 + wc*64 + n*16 + lr;
        store_c(&C[row * (long)N + col], acc[m][n][j]);
      }
}

// ---------------- GEMV for alpha/beta gates ----------------
__global__ __launch_bounds__(256) void gemv_ab_k(
    const float* __restrict__ X, const float* __restrict__ Wa, const float* __restrict__ Wb,
    const float* __restrict__ A_log, const float* __restrict__ dt_bias,
    float* __restrict__ alpha, float* __restrict__ beta)
{
  __shared__ float xs[CD];
  int row = blockIdx.x;
  int tid = threadIdx.x;
  ((float4*)xs)[tid] = ((const float4*)(X + (long)row * CD))[tid];
  __syncthreads();
  int g = tid >> 4, sL = tid & 15;
  int col = g & 7;
  const float* W = (g >= 8) ? Wb : Wa;
  float acc = 0.f;
  for (int k = sL; k < CD; k += 16) acc = fmaf(xs[k], W[k * 8 + col], acc);
  acc += __shfl_xor(acc, 1); acc += __shfl_xor(acc, 2);
  acc += __shfl_xor(acc, 4); acc += __shfl_xor(acc, 8);
  if (sL == 0){
    if (g < 8){
      float xv = acc + dt_bias[col];
      float sp = fmaxf(xv, 0.f) + log1pf(expf(-fabsf(xv)));
      alpha[(long)row * 8 + col] = expf(-expf(A_log[col]) * sp);
    } else {
      beta[(long)row * 8 + col] = sigm(acc);
    }
  }
}

// ---------------- causal depthwise conv + SiLU (+ head L2 norm) ----------------
template<int DH, bool NORM>
__global__ __launch_bounds__(DH) void conv_silu_k(
    const u16* __restrict__ pre, const float* __restrict__ cw, const float* __restrict__ cb,
    u16* __restrict__ out)
{
  int idx = blockIdx.x;
  int h = idx & 7;
  int t = (idx >> 3) & (CT - 1);
  int b = idx >> 14;
  int tidx = threadIdx.x;
  int ch = h * DH + tidx;
  const int C = CH * DH;
  long base = ((long)b * CT + t) * C + ch;
  float acc = cb[ch];
  #pragma unroll
  for (int j = 0; j < 4; j++){
    int tt = t - 3 + j;
    float x = (tt >= 0) ? b2f(pre[base + ((long)j - 3) * C]) : 0.f;
    acc = fmaf(cw[ch * 4 + j], x, acc);
  }
  float y = acc * sigm(acc);
  if (NORM){
    float ss = y * y;
    #pragma unroll
    for (int off = 1; off < 64; off <<= 1) ss += __shfl_xor(ss, off);
    __shared__ float wsum[DH / 64];
    if ((tidx & 63) == 0) wsum[tidx >> 6] = ss;
    __syncthreads();
    float tot = 0.f;
    #pragma unroll
    for (int i = 0; i < DH / 64; i++) tot += wsum[i];
    y *= 1.f / fmaxf(sqrtf(tot), 1e-12f);
  }
  out[base] = f2b(y);
}

// ---------------- sequential delta-rule scan ----------------
// One wave = 8 v-columns x full K (8 k-slices of 16). Reduction over k is
// wave-local (shfl_xor 8/16/32) -> NO per-step __syncthreads. One barrier per
// 16-step chunk for double-buffered LDS staging.
__global__ __launch_bounds__(256) void scan_kernel(
    const u16* __restrict__ qn, const u16* __restrict__ kn, const u16* __restrict__ vn,
    const float* __restrict__ alpha, const float* __restrict__ beta,
    const float* __restrict__ prev, float* __restrict__ obuf, float* __restrict__ fstate)
{
  constexpr int CHUNK = 16;
  constexpr int SLICE = CHUNK * 16 + 4;  // kq-block stride in floats (pad 16B -> conflict-free)
  int blk = blockIdx.x;
  int vs = blk & 7;
  int h = (blk >> 3) & 7;
  int b = blk >> 6;
  int tid = threadIdx.x;
  int lane = tid & 63;
  int wv = tid >> 6;
  int cl = lane & 7;      // column within wave
  int kq = lane >> 3;     // k-slice (16 elems)
  int colB = wv * 8 + cl; // column within block's 32
  int col = vs * 32 + colB;

  __shared__ float qs[2][8 * SLICE];
  __shared__ float ks[2][8 * SLICE];
  __shared__ float vsS[2][CHUNK][32];
  __shared__ float abS[2][CHUNK][2];

  // state: s[i] = S[kq*16+i][col]
  float s[16];
  {
    const float* pb = prev + ((long)(b * CH + h) * CDK + kq * 16) * CDV + col;
    #pragma unroll
    for (int i = 0; i < 16; i++) s[i] = pb[(long)i * CDV];
  }

  // staging: 256 threads load a 16-step chunk
  int sr  = tid >> 4;          // step row 0..15
  int scq = (tid & 15) * 8;    // q/k col offset (8 bf16 = 16B)
  int scv = (tid & 15) * 2;    // v col offset (2 bf16)
  ushort4 rq0, rq1, rk0, rk1; u32 rv = 0; float rab = 0.f;

  auto load_chunk = [&](int t0){
    long rowq = ((long)b * CT + t0 + sr) * CH + h;
    const ushort4* qp = (const ushort4*)(qn + rowq * CDK + scq);
    rq0 = qp[0]; rq1 = qp[1];
    const ushort4* kp = (const ushort4*)(kn + rowq * CDK + scq);
    rk0 = kp[0]; rk1 = kp[1];
    rv = *(const u32*)(vn + rowq * CDV + vs * 32 + scv);
    if (tid < 32){
      long rowr = ((long)b * CT + t0 + (tid & 15)) * CH + h;
      rab = (tid < 16) ? alpha[rowr] : beta[rowr];
    }
  };
  auto cvt4 = [](ushort4 u){ return make_float4(b2f(u.x), b2f(u.y), b2f(u.z), b2f(u.w)); };
  auto store_chunk = [&](int p){
    int base = (scq >> 4) * SLICE + sr * 16 + (scq & 15);
    *(float4*)&qs[p][base]     = cvt4(rq0);
    *(float4*)&qs[p][base + 4] = cvt4(rq1);
    *(float4*)&ks[p][base]     = cvt4(rk0);
    *(float4*)&ks[p][base + 4] = cvt4(rk1);
    vsS[p][sr][scv]     = b2f((u16)(rv & 0xffffu));
    vsS[p][sr][scv + 1] = b2f((u16)(rv >> 16));
    if (tid < 32) abS[p][tid & 15][tid >> 4] = rab;
  };

  load_chunk(0);
  const int NCH = CT / CHUNK;
  for (int chn = 0; chn < NCH; ++chn){
    int p = chn & 1;
    store_chunk(p);
    __syncthreads();
    if (chn + 1 < NCH) load_chunk((chn + 1) * CHUNK);

    long obase = (((long)b * CT + chn * CHUNK) * CH + h) * CDV + col;
    #pragma unroll 2
    for (int st = 0; st < CHUNK; ++st){
      float qf[16], kf[16];
      #pragma unroll
      for (int i = 0; i < 4; i++){
        *(float4*)&qf[i * 4] = *(const float4*)&qs[p][kq * SLICE + st * 16 + i * 4];
        *(float4*)&kf[i * 4] = *(const float4*)&ks[p][kq * SLICE + st * 16 + i * 4];
      }
      float vv = vsS[p][st][colB];
      float al = abS[p][st][0];
      float be = abS[p][st][1];
      float o0=0.f,o1=0.f,o2=0.f,o3=0.f,k0=0.f,k1=0.f,k2=0.f,k3=0.f;
      #pragma unroll
      for (int i = 0; i < 4; i++){
        o0 = fmaf(qf[i],      s[i],      o0);
        o1 = fmaf(qf[4 + i],  s[4 + i],  o1);
        o2 = fmaf(qf[8 + i],  s[8 + i],  o2);
        o3 = fmaf(qf[12 + i], s[12 + i], o3);
        k0 = fmaf(kf[i],      s[i],      k0);
        k1 = fmaf(kf[4 + i],  s[4 + i],  k1);
        k2 = fmaf(kf[8 + i],  s[8 + i],  k2);
        k3 = fmaf(kf[12 + i], s[12 + i], k3);
      }
      float po = (o0 + o1) + (o2 + o3);
      float pk = (k0 + k1) + (k2 + k3);
      po += __shfl_xor(po, 8);  pk += __shfl_xor(pk, 8);
      po += __shfl_xor(po, 16); pk += __shfl_xor(pk, 16);
      po += __shfl_xor(po, 32); pk += __shfl_xor(pk, 32);
      float bd = be * (vv - pk);
      #pragma unroll
      for (int i = 0; i < 16; i++) s[i] = fmaf(al, s[i], bd * kf[i]);
      if (kq == 0) obuf[obase + (long)st * CH * CDV] = po;
    }
  }
  float* fb = fstate + ((long)(b * CH + h) * CDK + kq * 16) * CDV + col;
  #pragma unroll
  for (int i = 0; i < 16; i++) fb[(long)i * CDV] = s[i];
}

// ---------------- gated RMSNorm: one wave per (b,t,h) ----------------
__global__ __launch_bounds__(256) void rms_gate_k(
    const float* __restrict__ o, const u16* __restrict__ gate,
    const float* __restrict__ nw, u16* __restrict__ ofin)
{
  long idx = (long)blockIdx.x * 4 + (threadIdx.x >> 6);
  int lane = threadIdx.x & 63;
  long base = idx * CDV + lane * 4;
  float4 ov = *(const float4*)(o + base);
  float ss = ov.x*ov.x + ov.y*ov.y + ov.z*ov.z + ov.w*ov.w;
  #pragma unroll
  for (int off = 1; off < 64; off <<= 1) ss += __shfl_xor(ss, off);
  float r = rsqrtf(ss * (1.f / CDV) + 1e-5f);
  ushort4 g4 = *(const ushort4*)(gate + base);
  float w0 = nw[lane*4], w1 = nw[lane*4+1], w2 = nw[lane*4+2], w3 = nw[lane*4+3];
  ushort4 res;
  res.x = f2b(ov.x * r * w0 * sigm(b2f(g4.x)));
  res.y = f2b(ov.y * r * w1 * sigm(b2f(g4.y)));
  res.z = f2b(ov.z * r * w2 * sigm(b2f(g4.z)));
  res.w = f2b(ov.w * r * w3 * sigm(b2f(g4.w)));
  *(ushort4*)(ofin + base) = res;
}

// ---------------- host launch ----------------
extern "C" void kernel_launch(void* const* d_in, const int* in_sizes, int n_in,
                              void* d_out, int out_size, void* d_ws, size_t ws_size,
                              hipStream_t stream)
{
  (void)in_sizes; (void)n_in; (void)out_size; (void)ws_size;
  const float* X    = (const float*)d_in[0];
  const float* prev = (const float*)d_in[1];
  const float* Wq   = (const float*)d_in[2];
  const float* Wk   = (const float*)d_in[3];
  const float* Wv   = (const float*)d_in[4];
  const float* Wa   = (const float*)d_in[5];
  const float* Wb   = (const float*)d_in[6];
  const float* Wg   = (const float*)d_in[7];
  const float* Wo   = (const float*)d_in[8];
  const float* qcw  = (const float*)d_in[9];
  const float* qcb  = (const float*)d_in[10];
  const float* kcw  = (const float*)d_in[11];
  const float* kcb  = (const float*)d_in[12];
  const float* vcw  = (const float*)d_in[13];
  const float* vcb  = (const float*)d_in[14];
  const float* onw  = (const float*)d_in[15];
  const float* Alog = (const float*)d_in[16];
  const float* dtb  = (const float*)d_in[17];

  float* out = (float*)d_out;
  float* fstate = out + (long)CB * CT * CD;

  char* ws = (char*)d_ws;
  size_t off = 0;
  auto alloc = [&](size_t bytes) -> char* {
    char* p = ws + off;
    off += (bytes + 255) & ~(size_t)255;
    return p;
  };
  u16* Xb   = (u16*)alloc(NROW * CD * 2);
  u16* Wqt  = (u16*)alloc((size_t)1024 * 1024 * 2);
  u16* Wkt  = (u16*)alloc((size_t)1024 * 1024 * 2);
  u16* Wvt  = (u16*)alloc((size_t)2048 * 1024 * 2);
  u16* Wgt  = (u16*)alloc((size_t)2048 * 1024 * 2);
  u16* Wot  = (u16*)alloc((size_t)1024 * 2048 * 2);
  u16* qpre = (u16*)alloc(NROW * 1024 * 2);
  u16* kpre = (u16*)alloc(NROW * 1024 * 2);
  u16* vpre = (u16*)alloc(NROW * 2048 * 2);
  u16* gpre = (u16*)alloc(NROW * 2048 * 2);
  float* alpha = (float*)alloc(NROW * 8 * 4);
  float* beta  = (float*)alloc(NROW * 8 * 4);
  u16* qn   = (u16*)alloc(NROW * 1024 * 2);
  u16* kn   = (u16*)alloc(NROW * 1024 * 2);
  u16* vn   = (u16*)alloc(NROW * 2048 * 2);
  u16* ofin = (u16*)alloc(NROW * 2048 * 2);
  // o (B,T,H,DV) f32 = 67MB reuses the dead qpre+kpre+vpre region (exactly 67MB)
  float* obuf = (float*)qpre;

  cast_f32_bf16_k<<<2048, 256, 0, stream>>>(X, Xb, NROW * CD / 4);
  transpose_cast_k<<<dim3(32, 32), 256, 0, stream>>>(Wq, Wqt, 1024, 1024);
  transpose_cast_k<<<dim3(32, 32), 256, 0, stream>>>(Wk, Wkt, 1024, 1024);
  transpose_cast_k<<<dim3(64, 32), 256, 0, stream>>>(Wv, Wvt, 1024, 2048);
  transpose_cast_k<<<dim3(64, 32), 256, 0, stream>>>(Wg, Wgt, 1024, 2048);
  transpose_cast_k<<<dim3(32, 64), 256, 0, stream>>>(Wo, Wot, 2048, 1024);

  gemm_nt<u16><<<dim3(8, 64), 256, 0, stream>>>(Xb, Wqt, qpre, 8192, 1024, 1024);
  gemm_nt<u16><<<dim3(8, 64), 256, 0, stream>>>(Xb, Wkt, kpre, 8192, 1024, 1024);
  gemm_nt<u16><<<dim3(16, 64), 256, 0, stream>>>(Xb, Wvt, vpre, 8192, 2048, 1024);
  gemm_nt<u16><<<dim3(16, 64), 256, 0, stream>>>(Xb, Wgt, gpre, 8192, 2048, 1024);
  gemv_ab_k<<<8192, 256, 0, stream>>>(X, Wa, Wb, Alog, dtb, alpha, beta);

  conv_silu_k<128, true><<<CB * CT * CH, 128, 0, stream>>>(qpre, qcw, qcb, qn);
  conv_silu_k<128, true><<<CB * CT * CH, 128, 0, stream>>>(kpre, kcw, kcb, kn);
  conv_silu_k<256, false><<<CB * CT * CH, 256, 0, stream>>>(vpre, vcw, vcb, vn);

  scan_kernel<<<CB * CH * 8, 256, 0, stream>>>(qn, kn, vn, alpha, beta, prev, obuf, fstate);

  rms_gate_k<<<CB * CT * CH / 4, 256, 0, stream>>>(obuf, gpre, onw, ofin);
  gemm_nt<float><<<dim3(8, 64), 256, 0, stream>>>(ofin, Wot, out, 8192, 1024, 2048);
}

// Round 3
// 741.000 us; speedup vs baseline: 2.1086x; 1.8252x over previous
//
#include <hip/hip_runtime.h>
#include <stdint.h>

typedef unsigned short u16;
typedef unsigned int u32;

#define DEVFN __device__ __forceinline__

constexpr int CB = 4;
constexpr int CT = 2048;
constexpr int CD = 1024;
constexpr int CH = 8;
constexpr int CDK = 128;
constexpr int CDV = 256;
constexpr long NROW = (long)CB * CT;   // 8192

DEVFN float b2f(u16 s){ return __uint_as_float(((u32)s) << 16); }
DEVFN u16 f2b(float f){
  u32 u = __float_as_uint(f);
  u32 r = (u + 0x7fffu + ((u >> 16) & 1u)) >> 16;
  return (u16)r;
}
DEVFN float sigm(float x){ return 1.f / (1.f + expf(-x)); }
DEVFN int swz3(int r){ return (r ^ (r >> 2)) & 3; }

// ---------------- cast X to bf16 ----------------
__global__ void cast_f32_bf16_k(const float* __restrict__ in, u16* __restrict__ out, long n4){
  long i = (long)blockIdx.x * blockDim.x + threadIdx.x;
  long stride = (long)gridDim.x * blockDim.x;
  for (; i < n4; i += stride){
    float4 v = ((const float4*)in)[i];
    ushort4 r;
    r.x = f2b(v.x); r.y = f2b(v.y); r.z = f2b(v.z); r.w = f2b(v.w);
    ((ushort4*)out)[i] = r;
  }
}

// ---------------- transpose + cast weights: W (K x N) f32 -> Wt (N x K) bf16 ----------------
__global__ __launch_bounds__(256) void transpose_cast_k(const float* __restrict__ W, u16* __restrict__ Wt, int K, int N){
  __shared__ float tile[32][33];
  int n0 = blockIdx.x * 32, k0 = blockIdx.y * 32;
  int tx = threadIdx.x & 31, ty = threadIdx.x >> 5;   // 32 x 8
  #pragma unroll
  for (int i = 0; i < 4; i++)
    tile[ty + 8*i][tx] = W[(long)(k0 + ty + 8*i) * N + n0 + tx];
  __syncthreads();
  #pragma unroll
  for (int i = 0; i < 4; i++){
    int nn = ty + 8*i;
    Wt[(long)(n0 + nn) * K + k0 + tx] = f2b(tile[tx][nn]);
  }
}

// ---------------- bf16 MFMA GEMM (NT): C[M,N] = A[M,K] * Bt[N,K]^T ----------------
typedef __bf16 bf16x8 __attribute__((ext_vector_type(8)));
typedef float f32x4 __attribute__((ext_vector_type(4)));

DEVFN void store_c(float* p, float v){ *p = v; }
DEVFN void store_c(u16* p, float v){ *p = f2b(v); }

DEVFN void gload16(const void* g, void* l){
  __builtin_amdgcn_global_load_lds((__attribute__((address_space(1))) void*)g,
                                   (__attribute__((address_space(3))) void*)l, 16, 0, 0);
}

template <typename OutT>
__global__ __launch_bounds__(256) void gemm_nt(
    const u16* __restrict__ A, const u16* __restrict__ Bt, OutT* __restrict__ C,
    int M, int N, int K)
{
  __shared__ u16 As[128 * 64];
  __shared__ u16 Bs[128 * 64];
  int tid = threadIdx.x;
  int w = tid >> 6, l = tid & 63;
  int wr = w >> 1, wc = w & 1;
  int m0 = blockIdx.y * 128, n0 = blockIdx.x * 128;

  f32x4 acc[4][4] = {};

  int chr = l >> 3;            // row within 8-row chunk
  int ckc = (l & 7) * 8;       // k element offset within 64
  const u16* Ab = A + (long)m0 * K;
  const u16* Bb = Bt + (long)n0 * K;
  int lr = l & 15, lk = (l >> 4) * 8;

  for (int k0 = 0; k0 < K; k0 += 64){
    #pragma unroll
    for (int i = 0; i < 4; i++){
      int chunk = w * 4 + i;
      int r = chunk * 8 + chr;
      gload16(Ab + (long)r * K + k0 + ckc, &As[chunk * 512 + l * 8]);
      gload16(Bb + (long)r * K + k0 + ckc, &Bs[chunk * 512 + l * 8]);
    }
    __syncthreads();
    #pragma unroll
    for (int kk = 0; kk < 64; kk += 32){
      bf16x8 av[4], bv[4];
      #pragma unroll
      for (int m = 0; m < 4; m++) av[m] = *(const bf16x8*)&As[(wr*64 + m*16 + lr)*64 + kk + lk];
      #pragma unroll
      for (int n = 0; n < 4; n++) bv[n] = *(const bf16x8*)&Bs[(wc*64 + n*16 + lr)*64 + kk + lk];
      #pragma unroll
      for (int m = 0; m < 4; m++)
        #pragma unroll
        for (int n = 0; n < 4; n++)
          acc[m][n] = __builtin_amdgcn_mfma_f32_16x16x32_bf16(av[m], bv[n], acc[m][n], 0, 0, 0);
    }
    __syncthreads();
  }

  int lg = l >> 4;
  #pragma unroll
  for (int m = 0; m < 4; m++)
    #pragma unroll
    for (int n = 0; n < 4; n++)
      #pragma unroll
      for (int j = 0; j < 4; j++){
        long row = m0 + wr*64 + m*16 + lg*4 + j;
        long col = n0 + wc*64 + n*16 + lr;
        store_c(&C[row * (long)N + col], acc[m][n][j]);
      }
}

// ---------------- GEMV for alpha/beta gates ----------------
__global__ __launch_bounds__(256) void gemv_ab_k(
    const float* __restrict__ X, const float* __restrict__ Wa, const float* __restrict__ Wb,
    const float* __restrict__ A_log, const float* __restrict__ dt_bias,
    float* __restrict__ alpha, float* __restrict__ beta)
{
  __shared__ float xs[CD];
  int row = blockIdx.x;
  int tid = threadIdx.x;
  ((float4*)xs)[tid] = ((const float4*)(X + (long)row * CD))[tid];
  __syncthreads();
  int g = tid >> 4, sL = tid & 15;
  int col = g & 7;
  const float* W = (g >= 8) ? Wb : Wa;
  float acc = 0.f;
  for (int k = sL; k < CD; k += 16) acc = fmaf(xs[k], W[k * 8 + col], acc);
  acc += __shfl_xor(acc, 1); acc += __shfl_xor(acc, 2);
  acc += __shfl_xor(acc, 4); acc += __shfl_xor(acc, 8);
  if (sL == 0){
    if (g < 8){
      float xv = acc + dt_bias[col];
      float sp = fmaxf(xv, 0.f) + log1pf(expf(-fabsf(xv)));
      alpha[(long)row * 8 + col] = expf(-expf(A_log[col]) * sp);
    } else {
      beta[(long)row * 8 + col] = sigm(acc);
    }
  }
}

// ---------------- causal depthwise conv + SiLU (+ head L2 norm) ----------------
template<int DH, bool NORM>
__global__ __launch_bounds__(DH) void conv_silu_k(
    const u16* __restrict__ pre, const float* __restrict__ cw, const float* __restrict__ cb,
    u16* __restrict__ out)
{
  int idx = blockIdx.x;
  int h = idx & 7;
  int t = (idx >> 3) & (CT - 1);
  int b = idx >> 14;
  int tidx = threadIdx.x;
  int ch = h * DH + tidx;
  const int C = CH * DH;
  long base = ((long)b * CT + t) * C + ch;
  float acc = cb[ch];
  #pragma unroll
  for (int j = 0; j < 4; j++){
    int tt = t - 3 + j;
    float x = (tt >= 0) ? b2f(pre[base + ((long)j - 3) * C]) : 0.f;
    acc = fmaf(cw[ch * 4 + j], x, acc);
  }
  float y = acc * sigm(acc);
  if (NORM){
    float ss = y * y;
    #pragma unroll
    for (int off = 1; off < 64; off <<= 1) ss += __shfl_xor(ss, off);
    __shared__ float wsum[DH / 64];
    if ((tidx & 63) == 0) wsum[tidx >> 6] = ss;
    __syncthreads();
    float tot = 0.f;
    #pragma unroll
    for (int i = 0; i < DH / 64; i++) tot += wsum[i];
    y *= 1.f / fmaxf(sqrtf(tot), 1e-12f);
  }
  out[base] = f2b(y);
}

// ============ chunked delta rule: per-chunk metadata (L=32) ============
// Per (b,h,chunk): Rk=K@K^T, Rq=Q@K^T (MFMA); A[i,s]=Rk*beta_s*e^{cum_i-cum_{s+1}} (s<i);
// Tinv=(I+A)^{-1} via static Gaussian elimination; P likewise from Rq;
// KTS[k][s] = K[s][k]*beta_s*e^{cum32-cum_{s+1}}; scal = {Gamma_i, Gtot}.
__global__ __launch_bounds__(256) void chunk_meta_k(
    const u16* __restrict__ qn, const u16* __restrict__ kn,
    const float* __restrict__ alpha, const float* __restrict__ beta,
    u16* __restrict__ Tinv_g, u16* __restrict__ P_g, u16* __restrict__ KTS_g,
    float* __restrict__ scal_g)
{
  int bid = blockIdx.x;
  int c = bid & 63, bh = bid >> 6;
  int b = bh >> 3, h = bh & 7;
  long rowb = (long)b * CT + c * 32;
  int tid = threadIdx.x, lane = tid & 63, wv = tid >> 6;
  int l15 = lane & 15, lhi = lane >> 4;
  int mt = wv & 1, nt = wv >> 1;

  __shared__ u16 Kc[4096], Qc[4096];
  __shared__ float Al[32 * 33];
  __shared__ float al_s[32], be_s[32], cums[33], bscal[32];

  #pragma unroll
  for (int p = 0; p < 2; p++){
    int X = p * 256 + tid; int r = X >> 4, jj = X & 15;
    gload16(kn + ((rowb + r) * 8 + h) * 128 + (jj ^ (r & 7)) * 8, &Kc[(size_t)X * 8]);
  }
  #pragma unroll
  for (int p = 0; p < 2; p++){
    int X = p * 256 + tid; int r = X >> 4, jj = X & 15;
    gload16(qn + ((rowb + r) * 8 + h) * 128 + (jj ^ (r & 7)) * 8, &Qc[(size_t)X * 8]);
  }
  if (tid < 32) al_s[tid] = alpha[(rowb + tid) * 8 + h];
  else if (tid < 64) be_s[tid - 32] = beta[(rowb + tid - 32) * 8 + h];
  __syncthreads();
  if (tid == 0){
    float cacc = 0.f; cums[0] = 0.f;
    for (int j = 0; j < 32; j++){ cacc += logf(al_s[j]); cums[j + 1] = cacc; }
  }
  __syncthreads();
  if (tid < 32) bscal[tid] = be_s[tid] * expf(cums[32] - cums[tid + 1]);
  asm volatile("s_waitcnt vmcnt(0)" ::: "memory");
  __syncthreads();

  f32x4 rk = {0.f,0.f,0.f,0.f}, rq = {0.f,0.f,0.f,0.f};
  int ra = mt * 16 + l15, rb = nt * 16 + l15;
  #pragma unroll
  for (int ks = 0; ks < 4; ks++){
    int slot = ks * 4 + lhi;
    bf16x8 ak = *(const bf16x8*)&Kc[ra * 128 + (slot ^ (ra & 7)) * 8];
    bf16x8 aq = *(const bf16x8*)&Qc[ra * 128 + (slot ^ (ra & 7)) * 8];
    bf16x8 bk = *(const bf16x8*)&Kc[rb * 128 + (slot ^ (rb & 7)) * 8];
    rk = __builtin_amdgcn_mfma_f32_16x16x32_bf16(ak, bk, rk, 0, 0, 0);
    rq = __builtin_amdgcn_mfma_f32_16x16x32_bf16(aq, bk, rq, 0, 0, 0);
  }
  int s_ = nt * 16 + l15;
  long pb_ = (long)bid * 1024;
  #pragma unroll
  for (int j = 0; j < 4; j++){
    int i_ = mt * 16 + lhi * 4 + j;
    float e = (s_ < i_) ? expf(cums[i_] - cums[s_ + 1]) * be_s[s_] : 0.f;
    Al[i_ * 33 + s_] = rk[j] * e;
    P_g[pb_ + i_ * 32 + s_] = f2b(rq[j] * e);
  }
  __syncthreads();

  if (tid < 32){
    float x[32];
    #pragma unroll
    for (int i = 0; i < 32; i++) x[i] = (i == tid) ? 1.f : 0.f;
    #pragma unroll
    for (int s = 0; s < 31; s++){
      float xs = x[s];
      #pragma unroll
      for (int i = s + 1; i < 32; i++) x[i] = fmaf(-Al[i * 33 + s], xs, x[i]);
    }
    #pragma unroll
    for (int i = 0; i < 32; i++) Tinv_g[pb_ + i * 32 + tid] = f2b(x[i]);
    scal_g[(long)bid * 48 + tid] = expf(cums[tid]);
    if (tid == 0) scal_g[(long)bid * 48 + 32] = expf(cums[32]);
  } else if (tid >= 64){
    int t0 = tid - 64;
    #pragma unroll
    for (int e2 = 0; e2 < 22; e2++){
      int e = t0 + e2 * 192;
      if (e < 4096){
        int k = e >> 5, s2 = e & 31;
        int slot = k >> 3;
        float kv = b2f(Kc[s2 * 128 + (slot ^ (s2 & 7)) * 8 + (k & 7)]);
        KTS_g[(long)bid * 4096 + k * 32 + s2] = f2b(kv * bscal[s2]);
      }
    }
  }
}

// ============ chunked delta rule: main scan (serial over 64 chunks) ============
// Block = (b,h, 32-col v-slice); state 128x32 fp32 in registers (MFMA C layout)
// + bf16 copy in LDS. Per chunk: W = Gamma o (S^T K^T); R = V - W; U = Tinv@R;
// O = Gamma o (S^T Q^T) + U@P^T; S' = Gtot*S + U@KTS^T.  All staged via
// global_load_lds with XOR-preswizzled sources; counted vmcnt keeps prefetch alive.
__global__ __launch_bounds__(256) void chunk_scan_k(
    const u16* __restrict__ qn, const u16* __restrict__ kn, const u16* __restrict__ vn,
    const u16* __restrict__ Tinv_g, const u16* __restrict__ P_g, const u16* __restrict__ KTS_g,
    const float* __restrict__ scal_g, const float* __restrict__ prev,
    float* __restrict__ obuf, float* __restrict__ fstate)
{
  int bid = blockIdx.x;
  int bh = bid & 31, vs = bid >> 5;        // same-bh blocks share XCD (bid%8==bh%8)
  int b = bh >> 3, h = bh & 7;
  int tid = threadIdx.x, lane = tid & 63, wv = tid >> 6;
  int l15 = lane & 15, lhi = lane >> 4;
  int mv = wv & 1, nn = wv >> 1;

  __shared__ u16 Kc[2][4096];
  __shared__ u16 Vs[2][1024];
  __shared__ float scal[2][48];
  __shared__ u16 Qc[4096];
  __shared__ u16 KT[4096];
  __shared__ u16 Ti[1024];
  __shared__ u16 Ps[1024];
  __shared__ u16 Sb[32 * 136];
  __shared__ u16 RU[32 * 40];
  __shared__ float Ost[32 * 36];

  auto issue_kcv = [&](int c, int bf){
    long rowb = (long)b * CT + c * 32;
    #pragma unroll
    for (int p = 0; p < 2; p++){
      int X = p * 256 + tid; int r = X >> 4, jj = X & 15;
      gload16(kn + ((rowb + r) * 8 + h) * 128 + (jj ^ (r & 7)) * 8, &Kc[bf][(size_t)X * 8]);
    }
    if (lane < 32){
      int X = wv * 32 + lane; int r = X >> 2, jj = X & 3;
      gload16(vn + ((rowb + r) * 8 + h) * 256 + vs * 32 + (jj ^ swz3(r)) * 8, &Vs[bf][(size_t)X * 8]);
    }
    long sbase = ((long)bh * 64 + c) * 48;
    #pragma unroll
    for (int p = 0; p < 3; p++){
      int X = wv * 3 + p;
      if (lane == 0) gload16(scal_g + sbase + X * 4, &scal[bf][X * 4]);
    }
  };
  auto issue_rest = [&](int c){
    long rowb = (long)b * CT + c * 32;
    #pragma unroll
    for (int p = 0; p < 2; p++){
      int X = p * 256 + tid; int r = X >> 4, jj = X & 15;
      gload16(qn + ((rowb + r) * 8 + h) * 128 + (jj ^ (r & 7)) * 8, &Qc[(size_t)X * 8]);
    }
    long cb_ = (long)bh * 64 + c;
    const u16* Kb_ = KTS_g + cb_ * 4096;
    #pragma unroll
    for (int p = 0; p < 2; p++){
      int X = p * 256 + tid; int r = X >> 2, jj = X & 3;
      gload16(Kb_ + (r * 4 + (jj ^ swz3(r))) * 8, &KT[(size_t)X * 8]);
    }
    {
      int X = wv * 64 + lane;
      if (wv < 2){
        int r = X >> 2, jj = X & 3;
        gload16(Tinv_g + cb_ * 1024 + (r * 4 + (jj ^ swz3(r))) * 8, &Ti[(size_t)X * 8]);
      } else {
        int x2 = X - 128; int r = x2 >> 2, jj = x2 & 3;
        gload16(P_g + cb_ * 1024 + (r * 4 + (jj ^ swz3(r))) * 8, &Ps[(size_t)x2 * 8]);
      }
    }
  };

  // ---- prologue
  issue_kcv(0, 0);
  f32x4 st[4];
  {
    const float* pbv = prev + ((long)bh * 128) * 256 + vs * 32;
    #pragma unroll
    for (int tt = 0; tt < 4; tt++){
      int k = (nn * 4 + tt) * 16 + l15;
      #pragma unroll
      for (int j = 0; j < 4; j++){
        int v = mv * 16 + lhi * 4 + j;
        st[tt][j] = pbv[(long)k * 256 + v];
      }
    }
  }
  #pragma unroll
  for (int tt = 0; tt < 4; tt++){
    int k = (nn * 4 + tt) * 16 + l15;
    #pragma unroll
    for (int j = 0; j < 4; j++){
      int v = mv * 16 + lhi * 4 + j;
      Sb[v * 136 + k] = f2b(st[tt][j]);
    }
  }
  asm volatile("s_waitcnt lgkmcnt(0)" ::: "memory");
  __builtin_amdgcn_s_barrier();

  for (int c = 0; c < 64; ++c){
    int cb = c & 1;
    issue_rest(c);
    asm volatile("s_waitcnt vmcnt(5)" ::: "memory");
    __builtin_amdgcn_s_barrier();

    // ---- phase C: W = Gamma o (Sb^T Kc^T); R = V - W -> RU
    f32x4 wacc = {0.f,0.f,0.f,0.f};
    {
      int rv = mv * 16 + l15, rs = nn * 16 + l15;
      #pragma unroll
      for (int ks = 0; ks < 4; ks++){
        bf16x8 af = *(const bf16x8*)&Sb[rv * 136 + ks * 32 + lhi * 8];
        int slot = ks * 4 + lhi;
        bf16x8 bf_ = *(const bf16x8*)&Kc[cb][rs * 128 + (slot ^ (rs & 7)) * 8];
        wacc = __builtin_amdgcn_mfma_f32_16x16x32_bf16(af, bf_, wacc, 0, 0, 0);
      }
    }
    if (c + 1 < 64) issue_kcv(c + 1, cb ^ 1);
    {
      int s2 = nn * 16 + l15;
      float gs = scal[cb][s2];
      #pragma unroll
      for (int j = 0; j < 4; j++){
        int v = mv * 16 + lhi * 4 + j;
        float vv = b2f(Vs[cb][s2 * 32 + ((v >> 3) ^ swz3(s2)) * 8 + (v & 7)]);
        RU[v * 40 + s2] = f2b(vv - gs * wacc[j]);
      }
    }
    asm volatile("s_waitcnt lgkmcnt(0)" ::: "memory");
    if (c == 63) asm volatile("s_waitcnt vmcnt(0)" ::: "memory");
    else         asm volatile("s_waitcnt vmcnt(6)" ::: "memory");
    __builtin_amdgcn_s_barrier();

    // ---- phase E: U = Tinv @ R
    f32x4 uacc;
    {
      int rv = mv * 16 + l15, ri = nn * 16 + l15;
      bf16x8 aU = *(const bf16x8*)&RU[rv * 40 + lhi * 8];
      bf16x8 bT = *(const bf16x8*)&Ti[ri * 32 + (lhi ^ swz3(ri)) * 8];
      f32x4 z = {0.f,0.f,0.f,0.f};
      uacc = __builtin_amdgcn_mfma_f32_16x16x32_bf16(aU, bT, z, 0, 0, 0);
    }
    asm volatile("s_waitcnt lgkmcnt(0)" ::: "memory");
    __builtin_amdgcn_s_barrier();
    {
      int i_ = nn * 16 + l15;
      #pragma unroll
      for (int j = 0; j < 4; j++){
        int v = mv * 16 + lhi * 4 + j;
        RU[v * 40 + i_] = f2b(uacc[j]);
      }
    }
    asm volatile("s_waitcnt lgkmcnt(0)" ::: "memory");
    __builtin_amdgcn_s_barrier();

    // ---- phase F: O2 = U@P^T ; O1 = Sb^T Qc^T ; S' = Gtot*S + U@KTS^T
    f32x4 oacc, o1 = {0.f,0.f,0.f,0.f};
    float Gt = scal[cb][32];
    {
      int rv = mv * 16 + l15, ri = nn * 16 + l15;
      bf16x8 aU2 = *(const bf16x8*)&RU[rv * 40 + lhi * 8];
      bf16x8 bP = *(const bf16x8*)&Ps[ri * 32 + (lhi ^ swz3(ri)) * 8];
      f32x4 z = {0.f,0.f,0.f,0.f};
      oacc = __builtin_amdgcn_mfma_f32_16x16x32_bf16(aU2, bP, z, 0, 0, 0);
      #pragma unroll
      for (int ks = 0; ks < 4; ks++){
        bf16x8 aS = *(const bf16x8*)&Sb[rv * 136 + ks * 32 + lhi * 8];
        int slot = ks * 4 + lhi;
        bf16x8 bQ = *(const bf16x8*)&Qc[ri * 128 + (slot ^ (ri & 7)) * 8];
        o1 = __builtin_amdgcn_mfma_f32_16x16x32_bf16(aS, bQ, o1, 0, 0, 0);
      }
      #pragma unroll
      for (int tt = 0; tt < 4; tt++){
        int rk_ = (nn * 4 + tt) * 16 + l15;
        bf16x8 bK = *(const bf16x8*)&KT[rk_ * 32 + (lhi ^ swz3(rk_)) * 8];
        f32x4 ci = st[tt] * Gt;
        st[tt] = __builtin_amdgcn_mfma_f32_16x16x32_bf16(aU2, bK, ci, 0, 0, 0);
      }
    }
    asm volatile("s_waitcnt lgkmcnt(0)" ::: "memory");
    __builtin_amdgcn_s_barrier();

    // ---- phase G: write O to Ost, Sb-new; then coalesced obuf store
    {
      int i_ = nn * 16 + l15;
      float gi = scal[cb][i_];
      #pragma unroll
      for (int j = 0; j < 4; j++){
        int v = mv * 16 + lhi * 4 + j;
        Ost[i_ * 36 + v] = oacc[j] + gi * o1[j];
      }
      #pragma unroll
      for (int tt = 0; tt < 4; tt++){
        int k = (nn * 4 + tt) * 16 + l15;
        #pragma unroll
        for (int j = 0; j < 4; j++){
          int v = mv * 16 + lhi * 4 + j;
          Sb[v * 136 + k] = f2b(st[tt][j]);
        }
      }
    }
    asm volatile("s_waitcnt lgkmcnt(0)" ::: "memory");
    __builtin_amdgcn_s_barrier();
    {
      int r = tid >> 3, c4 = (tid & 7) * 4;
      float4 ov = *(const float4*)&Ost[r * 36 + c4];
      *(float4*)&obuf[(((long)bh * CT) + c * 32 + r) * 256 + vs * 32 + c4] = ov;
    }
  }

  // ---- epilogue: final state
  {
    float* fb = fstate + ((long)bh * 128) * 256 + vs * 32;
    #pragma unroll
    for (int tt = 0; tt < 4; tt++){
      int k = (nn * 4 + tt) * 16 + l15;
      #pragma unroll
      for (int j = 0; j < 4; j++){
        int v = mv * 16 + lhi * 4 + j;
        fb[(long)k * 256 + v] = st[tt][j];
      }
    }
  }
}

// ---------------- gated RMSNorm: one wave per (b,t,h) ----------------
// o is [b][h][t][256]; gate/ofin are [b][t][h*256]
__global__ __launch_bounds__(256) void rms_gate_k(
    const float* __restrict__ o, const u16* __restrict__ gate,
    const float* __restrict__ nw, u16* __restrict__ ofin)
{
  long idx = (long)blockIdx.x * 4 + (threadIdx.x >> 6);  // (b,t,h) linear
  int lane = threadIdx.x & 63;
  int h = (int)(idx & 7);
  long bt = idx >> 3;
  int b = (int)(bt >> 11);
  long t = bt & (CT - 1);
  long obase = (((long)(b * 8 + h)) * CT + t) * CDV + lane * 4;
  long base = idx * CDV + lane * 4;
  float4 ov = *(const float4*)(o + obase);
  float ss = ov.x*ov.x + ov.y*ov.y + ov.z*ov.z + ov.w*ov.w;
  #pragma unroll
  for (int off = 1; off < 64; off <<= 1) ss += __shfl_xor(ss, off);
  float r = rsqrtf(ss * (1.f / CDV) + 1e-5f);
  ushort4 g4 = *(const ushort4*)(gate + base);
  float w0 = nw[lane*4], w1 = nw[lane*4+1], w2 = nw[lane*4+2], w3 = nw[lane*4+3];
  ushort4 res;
  res.x = f2b(ov.x * r * w0 * sigm(b2f(g4.x)));
  res.y = f2b(ov.y * r * w1 * sigm(b2f(g4.y)));
  res.z = f2b(ov.z * r * w2 * sigm(b2f(g4.z)));
  res.w = f2b(ov.w * r * w3 * sigm(b2f(g4.w)));
  *(ushort4*)(ofin + base) = res;
}

// ---------------- host launch ----------------
extern "C" void kernel_launch(void* const* d_in, const int* in_sizes, int n_in,
                              void* d_out, int out_size, void* d_ws, size_t ws_size,
                              hipStream_t stream)
{
  (void)in_sizes; (void)n_in; (void)out_size; (void)ws_size;
  const float* X    = (const float*)d_in[0];
  const float* prev = (const float*)d_in[1];
  const float* Wq   = (const float*)d_in[2];
  const float* Wk   = (const float*)d_in[3];
  const float* Wv   = (const float*)d_in[4];
  const float* Wa   = (const float*)d_in[5];
  const float* Wb   = (const float*)d_in[6];
  const float* Wg   = (const float*)d_in[7];
  const float* Wo   = (const float*)d_in[8];
  const float* qcw  = (const float*)d_in[9];
  const float* qcb  = (const float*)d_in[10];
  const float* kcw  = (const float*)d_in[11];
  const float* kcb  = (const float*)d_in[12];
  const float* vcw  = (const float*)d_in[13];
  const float* vcb  = (const float*)d_in[14];
  const float* onw  = (const float*)d_in[15];
  const float* Alog = (const float*)d_in[16];
  const float* dtb  = (const float*)d_in[17];

  float* out = (float*)d_out;
  float* fstate = out + (long)CB * CT * CD;

  char* ws = (char*)d_ws;
  size_t off = 0;
  auto alloc = [&](size_t bytes) -> char* {
    char* p = ws + off;
    off += (bytes + 255) & ~(size_t)255;
    return p;
  };
  u16* Xb   = (u16*)alloc(NROW * CD * 2);
  u16* Wqt  = (u16*)alloc((size_t)1024 * 1024 * 2);
  u16* Wkt  = (u16*)alloc((size_t)1024 * 1024 * 2);
  u16* Wvt  = (u16*)alloc((size_t)2048 * 1024 * 2);
  u16* Wgt  = (u16*)alloc((size_t)2048 * 1024 * 2);
  u16* Wot  = (u16*)alloc((size_t)1024 * 2048 * 2);
  u16* qpre = (u16*)alloc(NROW * 1024 * 2);
  u16* kpre = (u16*)alloc(NROW * 1024 * 2);
  u16* vpre = (u16*)alloc(NROW * 2048 * 2);
  u16* gpre = (u16*)alloc(NROW * 2048 * 2);
  float* alpha = (float*)alloc(NROW * 8 * 4);
  float* beta  = (float*)alloc(NROW * 8 * 4);
  u16* qn   = (u16*)alloc(NROW * 1024 * 2);
  u16* kn   = (u16*)alloc(NROW * 1024 * 2);
  u16* vn   = (u16*)alloc(NROW * 2048 * 2);
  u16* ofin = (u16*)alloc(NROW * 2048 * 2);
  // o (B,H,T,DV) f32 = 67MB reuses the dead qpre+kpre+vpre region (exactly 67MB)
  float* obuf = (float*)qpre;
  // chunk metadata aliases: KTS -> Xb (16.78MB exact); Tinv/P/scal -> Wqt..Wgt (12MB)
  u16* KTS_g  = Xb;
  u16* Tinv_g = Wqt;
  u16* P_g    = Tinv_g + (size_t)2048 * 1024;
  float* scal_g = (float*)(P_g + (size_t)2048 * 1024);

  cast_f32_bf16_k<<<2048, 256, 0, stream>>>(X, Xb, NROW * CD / 4);
  transpose_cast_k<<<dim3(32, 32), 256, 0, stream>>>(Wq, Wqt, 1024, 1024);
  transpose_cast_k<<<dim3(32, 32), 256, 0, stream>>>(Wk, Wkt, 1024, 1024);
  transpose_cast_k<<<dim3(64, 32), 256, 0, stream>>>(Wv, Wvt, 1024, 2048);
  transpose_cast_k<<<dim3(64, 32), 256, 0, stream>>>(Wg, Wgt, 1024, 2048);
  transpose_cast_k<<<dim3(32, 64), 256, 0, stream>>>(Wo, Wot, 2048, 1024);

  gemm_nt<u16><<<dim3(8, 64), 256, 0, stream>>>(Xb, Wqt, qpre, 8192, 1024, 1024);
  gemm_nt<u16><<<dim3(8, 64), 256, 0, stream>>>(Xb, Wkt, kpre, 8192, 1024, 1024);
  gemm_nt<u16><<<dim3(16, 64), 256, 0, stream>>>(Xb, Wvt, vpre, 8192, 2048, 1024);
  gemm_nt<u16><<<dim3(16, 64), 256, 0, stream>>>(Xb, Wgt, gpre, 8192, 2048, 1024);
  gemv_ab_k<<<8192, 256, 0, stream>>>(X, Wa, Wb, Alog, dtb, alpha, beta);

  conv_silu_k<128, true><<<CB * CT * CH, 128, 0, stream>>>(qpre, qcw, qcb, qn);
  conv_silu_k<128, true><<<CB * CT * CH, 128, 0, stream>>>(kpre, kcw, kcb, kn);
  conv_silu_k<256, false><<<CB * CT * CH, 256, 0, stream>>>(vpre, vcw, vcb, vn);

  chunk_meta_k<<<2048, 256, 0, stream>>>(qn, kn, alpha, beta, Tinv_g, P_g, KTS_g, scal_g);
  chunk_scan_k<<<256, 256, 0, stream>>>(qn, kn, vn, Tinv_g, P_g, KTS_g, scal_g,
                                        prev, obuf, fstate);

  rms_gate_k<<<CB * CT * CH / 4, 256, 0, stream>>>(obuf, gpre, onw, ofin);
  gemm_nt<float><<<dim3(8, 64), 256, 0, stream>>>(ofin, Wot, out, 8192, 1024, 2048);
}

// Round 4
// 518.071 us; speedup vs baseline: 3.0159x; 1.4303x over previous
//
#include <hip/hip_runtime.h>
#include <stdint.h>

typedef unsigned short u16;
typedef unsigned int u32;

#define DEVFN __device__ __forceinline__

constexpr int CB = 4;
constexpr int CT = 2048;
constexpr int CD = 1024;
constexpr int CH = 8;
constexpr int CDK = 128;
constexpr int CDV = 256;
constexpr long NROW = (long)CB * CT;   // 8192

DEVFN float b2f(u16 s){ return __uint_as_float(((u32)s) << 16); }
DEVFN u16 f2b(float f){
  u32 u = __float_as_uint(f);
  u32 r = (u + 0x7fffu + ((u >> 16) & 1u)) >> 16;
  return (u16)r;
}
DEVFN float sigm(float x){ return 1.f / (1.f + expf(-x)); }
DEVFN int swz3(int r){ return (r ^ (r >> 2)) & 3; }

// ---------------- cast X to bf16 ----------------
__global__ void cast_f32_bf16_k(const float* __restrict__ in, u16* __restrict__ out, long n4){
  long i = (long)blockIdx.x * blockDim.x + threadIdx.x;
  long stride = (long)gridDim.x * blockDim.x;
  for (; i < n4; i += stride){
    float4 v = ((const float4*)in)[i];
    ushort4 r;
    r.x = f2b(v.x); r.y = f2b(v.y); r.z = f2b(v.z); r.w = f2b(v.w);
    ((ushort4*)out)[i] = r;
  }
}

// ---------------- transpose + cast weights: W (K x N) f32 -> Wt (N x K) bf16 ----------------
__global__ __launch_bounds__(256) void transpose_cast_k(const float* __restrict__ W, u16* __restrict__ Wt, int K, int N){
  __shared__ float tile[32][33];
  int n0 = blockIdx.x * 32, k0 = blockIdx.y * 32;
  int tx = threadIdx.x & 31, ty = threadIdx.x >> 5;   // 32 x 8
  #pragma unroll
  for (int i = 0; i < 4; i++)
    tile[ty + 8*i][tx] = W[(long)(k0 + ty + 8*i) * N + n0 + tx];
  __syncthreads();
  #pragma unroll
  for (int i = 0; i < 4; i++){
    int nn = ty + 8*i;
    Wt[(long)(n0 + nn) * K + k0 + tx] = f2b(tile[tx][nn]);
  }
}

// ---------------- bf16 MFMA GEMM (NT): C[M,N] = A[M,K] * Bt[N,K]^T ----------------
typedef __bf16 bf16x8 __attribute__((ext_vector_type(8)));
typedef float f32x4 __attribute__((ext_vector_type(4)));

DEVFN void store_c(float* p, float v){ *p = v; }
DEVFN void store_c(u16* p, float v){ *p = f2b(v); }

DEVFN void gload16(const void* g, void* l){
  __builtin_amdgcn_global_load_lds((__attribute__((address_space(1))) void*)g,
                                   (__attribute__((address_space(3))) void*)l, 16, 0, 0);
}

template <typename OutT>
__global__ __launch_bounds__(256) void gemm_nt(
    const u16* __restrict__ A, const u16* __restrict__ Bt, OutT* __restrict__ C,
    int M, int N, int K)
{
  __shared__ u16 As[128 * 64];
  __shared__ u16 Bs[128 * 64];
  int tid = threadIdx.x;
  int w = tid >> 6, l = tid & 63;
  int wr = w >> 1, wc = w & 1;
  int m0 = blockIdx.y * 128, n0 = blockIdx.x * 128;

  f32x4 acc[4][4] = {};

  int chr = l >> 3;            // row within 8-row chunk
  int ckc = (l & 7) * 8;       // k element offset within 64
  const u16* Ab = A + (long)m0 * K;
  const u16* Bb = Bt + (long)n0 * K;
  int lr = l & 15, lk = (l >> 4) * 8;

  for (int k0 = 0; k0 < K; k0 += 64){
    #pragma unroll
    for (int i = 0; i < 4; i++){
      int chunk = w * 4 + i;
      int r = chunk * 8 + chr;
      gload16(Ab + (long)r * K + k0 + ckc, &As[chunk * 512 + l * 8]);
      gload16(Bb + (long)r * K + k0 + ckc, &Bs[chunk * 512 + l * 8]);
    }
    __syncthreads();
    #pragma unroll
    for (int kk = 0; kk < 64; kk += 32){
      bf16x8 av[4], bv[4];
      #pragma unroll
      for (int m = 0; m < 4; m++) av[m] = *(const bf16x8*)&As[(wr*64 + m*16 + lr)*64 + kk + lk];
      #pragma unroll
      for (int n = 0; n < 4; n++) bv[n] = *(const bf16x8*)&Bs[(wc*64 + n*16 + lr)*64 + kk + lk];
      #pragma unroll
      for (int m = 0; m < 4; m++)
        #pragma unroll
        for (int n = 0; n < 4; n++)
          acc[m][n] = __builtin_amdgcn_mfma_f32_16x16x32_bf16(av[m], bv[n], acc[m][n], 0, 0, 0);
    }
    __syncthreads();
  }

  int lg = l >> 4;
  #pragma unroll
  for (int m = 0; m < 4; m++)
    #pragma unroll
    for (int n = 0; n < 4; n++)
      #pragma unroll
      for (int j = 0; j < 4; j++){
        long row = m0 + wr*64 + m*16 + lg*4 + j;
        long col = n0 + wc*64 + n*16 + lr;
        store_c(&C[row * (long)N + col], acc[m][n][j]);
      }
}

// ---------------- Wab pack: Wa(1024x8), Wb(1024x8) f32 -> Wab(16x1024) bf16 ----------------
__global__ __launch_bounds__(256) void build_wab_k(
    const float* __restrict__ Wa, const float* __restrict__ Wb, u16* __restrict__ Wab)
{
  int idx = blockIdx.x * 256 + threadIdx.x;   // 16384
  int c = idx >> 10, k = idx & 1023;
  float v = (c < 8) ? Wa[k * 8 + c] : Wb[k * 8 + (c - 8)];
  Wab[c * 1024 + k] = f2b(v);
}

// ---------------- alpha/beta via MFMA: C[8192x16] = Xb @ Wab^T, then activations ----------------
__global__ __launch_bounds__(256) void ab_mfma_k(
    const u16* __restrict__ Xb, const u16* __restrict__ Wab,
    const float* __restrict__ A_log, const float* __restrict__ dt_bias,
    float* __restrict__ alpha, float* __restrict__ beta)
{
  __shared__ u16 Ws[16 * 1024];   // 32KB, source-preswizzled (slot ^ (row&7))
  int tid = threadIdx.x, lane = tid & 63, wv = tid >> 6;
  #pragma unroll
  for (int p = 0; p < 8; p++){
    int X = p * 256 + tid;            // 16B slot id, 2048 total
    int r = X >> 7, s = X & 127;
    gload16(Wab + r * 1024 + (s ^ (r & 7)) * 8, &Ws[(size_t)X * 8]);
  }
  int l15 = lane & 15, lhi = lane >> 4;
  int row0 = blockIdx.x * 64 + wv * 16;
  const u16* Arow = Xb + (long)(row0 + l15) * 1024 + lhi * 8;
  __syncthreads();

  f32x4 acc = {0.f, 0.f, 0.f, 0.f};
  #pragma unroll 8
  for (int ks = 0; ks < 32; ks++){
    bf16x8 av = *(const bf16x8*)(Arow + ks * 32);
    int slot = ks * 4 + lhi;
    bf16x8 bv = *(const bf16x8*)&Ws[l15 * 1024 + (slot ^ (l15 & 7)) * 8];
    acc = __builtin_amdgcn_mfma_f32_16x16x32_bf16(av, bv, acc, 0, 0, 0);
  }

  int col = l15;
  float nA = 0.f, db = 0.f;
  if (col < 8){ nA = -expf(A_log[col]); db = dt_bias[col]; }
  #pragma unroll
  for (int j = 0; j < 4; j++){
    long row = row0 + lhi * 4 + j;
    float v = acc[j];
    if (col < 8){
      float xv = v + db;
      float sp = fmaxf(xv, 0.f) + log1pf(expf(-fabsf(xv)));
      alpha[row * 8 + col] = expf(nA * sp);
    } else {
      beta[row * 8 + (col - 8)] = sigm(v);
    }
  }
}

// ---------------- causal depthwise conv + SiLU (+ head L2 norm) ----------------
template<int DH, bool NORM>
__global__ __launch_bounds__(DH) void conv_silu_k(
    const u16* __restrict__ pre, const float* __restrict__ cw, const float* __restrict__ cb,
    u16* __restrict__ out)
{
  int idx = blockIdx.x;
  int h = idx & 7;
  int t = (idx >> 3) & (CT - 1);
  int b = idx >> 14;
  int tidx = threadIdx.x;
  int ch = h * DH + tidx;
  const int C = CH * DH;
  long base = ((long)b * CT + t) * C + ch;
  float acc = cb[ch];
  #pragma unroll
  for (int j = 0; j < 4; j++){
    int tt = t - 3 + j;
    float x = (tt >= 0) ? b2f(pre[base + ((long)j - 3) * C]) : 0.f;
    acc = fmaf(cw[ch * 4 + j], x, acc);
  }
  float y = acc * sigm(acc);
  if (NORM){
    float ss = y * y;
    #pragma unroll
    for (int off = 1; off < 64; off <<= 1) ss += __shfl_xor(ss, off);
    __shared__ float wsum[DH / 64];
    if ((tidx & 63) == 0) wsum[tidx >> 6] = ss;
    __syncthreads();
    float tot = 0.f;
    #pragma unroll
    for (int i = 0; i < DH / 64; i++) tot += wsum[i];
    y *= 1.f / fmaxf(sqrtf(tot), 1e-12f);
  }
  out[base] = f2b(y);
}

// ============ chunked delta rule: per-chunk metadata (L=32) ============
__global__ __launch_bounds__(256) void chunk_meta_k(
    const u16* __restrict__ qn, const u16* __restrict__ kn,
    const float* __restrict__ alpha, const float* __restrict__ beta,
    u16* __restrict__ Tinv_g, u16* __restrict__ P_g, u16* __restrict__ KTS_g,
    float* __restrict__ scal_g)
{
  int bid = blockIdx.x;
  int c = bid & 63, bh = bid >> 6;
  int b = bh >> 3, h = bh & 7;
  long rowb = (long)b * CT + c * 32;
  int tid = threadIdx.x, lane = tid & 63, wv = tid >> 6;
  int l15 = lane & 15, lhi = lane >> 4;
  int mt = wv & 1, nt = wv >> 1;

  __shared__ u16 Kc[4096], Qc[4096];
  __shared__ float Al[32 * 33];
  __shared__ float al_s[32], be_s[32], cums[33], bscal[32];

  #pragma unroll
  for (int p = 0; p < 2; p++){
    int X = p * 256 + tid; int r = X >> 4, jj = X & 15;
    gload16(kn + ((rowb + r) * 8 + h) * 128 + (jj ^ (r & 7)) * 8, &Kc[(size_t)X * 8]);
  }
  #pragma unroll
  for (int p = 0; p < 2; p++){
    int X = p * 256 + tid; int r = X >> 4, jj = X & 15;
    gload16(qn + ((rowb + r) * 8 + h) * 128 + (jj ^ (r & 7)) * 8, &Qc[(size_t)X * 8]);
  }
  if (tid < 32) al_s[tid] = alpha[(rowb + tid) * 8 + h];
  else if (tid < 64) be_s[tid - 32] = beta[(rowb + tid - 32) * 8 + h];
  __syncthreads();
  if (tid == 0){
    float cacc = 0.f; cums[0] = 0.f;
    for (int j = 0; j < 32; j++){ cacc += logf(al_s[j]); cums[j + 1] = cacc; }
  }
  __syncthreads();
  if (tid < 32) bscal[tid] = be_s[tid] * expf(cums[32] - cums[tid + 1]);
  asm volatile("s_waitcnt vmcnt(0)" ::: "memory");
  __syncthreads();

  f32x4 rk = {0.f,0.f,0.f,0.f}, rq = {0.f,0.f,0.f,0.f};
  int ra = mt * 16 + l15, rb = nt * 16 + l15;
  #pragma unroll
  for (int ks = 0; ks < 4; ks++){
    int slot = ks * 4 + lhi;
    bf16x8 ak = *(const bf16x8*)&Kc[ra * 128 + (slot ^ (ra & 7)) * 8];
    bf16x8 aq = *(const bf16x8*)&Qc[ra * 128 + (slot ^ (ra & 7)) * 8];
    bf16x8 bk = *(const bf16x8*)&Kc[rb * 128 + (slot ^ (rb & 7)) * 8];
    rk = __builtin_amdgcn_mfma_f32_16x16x32_bf16(ak, bk, rk, 0, 0, 0);
    rq = __builtin_amdgcn_mfma_f32_16x16x32_bf16(aq, bk, rq, 0, 0, 0);
  }
  int s_ = nt * 16 + l15;
  long pb_ = (long)bid * 1024;
  #pragma unroll
  for (int j = 0; j < 4; j++){
    int i_ = mt * 16 + lhi * 4 + j;
    float e = (s_ < i_) ? expf(cums[i_] - cums[s_ + 1]) * be_s[s_] : 0.f;
    Al[i_ * 33 + s_] = rk[j] * e;
    P_g[pb_ + i_ * 32 + s_] = f2b(rq[j] * e);
  }
  __syncthreads();

  if (tid < 32){
    float x[32];
    #pragma unroll
    for (int i = 0; i < 32; i++) x[i] = (i == tid) ? 1.f : 0.f;
    #pragma unroll
    for (int s = 0; s < 31; s++){
      float xs = x[s];
      #pragma unroll
      for (int i = s + 1; i < 32; i++) x[i] = fmaf(-Al[i * 33 + s], xs, x[i]);
    }
    #pragma unroll
    for (int i = 0; i < 32; i++) Tinv_g[pb_ + i * 32 + tid] = f2b(x[i]);
    scal_g[(long)bid * 48 + tid] = expf(cums[tid]);
    if (tid == 0) scal_g[(long)bid * 48 + 32] = expf(cums[32]);
  } else if (tid >= 64){
    int t0 = tid - 64;
    #pragma unroll
    for (int e2 = 0; e2 < 22; e2++){
      int e = t0 + e2 * 192;
      if (e < 4096){
        int k = e >> 5, s2 = e & 31;
        int slot = k >> 3;
        float kv = b2f(Kc[s2 * 128 + (slot ^ (s2 & 7)) * 8 + (k & 7)]);
        KTS_g[(long)bid * 4096 + k * 32 + s2] = f2b(kv * bscal[s2]);
      }
    }
  }
}

// ============ chunked delta rule: main scan (serial over 64 chunks) ============
__global__ __launch_bounds__(256) void chunk_scan_k(
    const u16* __restrict__ qn, const u16* __restrict__ kn, const u16* __restrict__ vn,
    const u16* __restrict__ Tinv_g, const u16* __restrict__ P_g, const u16* __restrict__ KTS_g,
    const float* __restrict__ scal_g, const float* __restrict__ prev,
    float* __restrict__ obuf, float* __restrict__ fstate)
{
  int bid = blockIdx.x;
  int bh = bid & 31, vs = bid >> 5;        // same-bh blocks share XCD (bid%8==bh%8)
  int b = bh >> 3, h = bh & 7;
  int tid = threadIdx.x, lane = tid & 63, wv = tid >> 6;
  int l15 = lane & 15, lhi = lane >> 4;
  int mv = wv & 1, nn = wv >> 1;

  __shared__ u16 Kc[2][4096];
  __shared__ u16 Vs[2][1024];
  __shared__ float scal[2][48];
  __shared__ u16 Qc[4096];
  __shared__ u16 KT[4096];
  __shared__ u16 Ti[1024];
  __shared__ u16 Ps[1024];
  __shared__ u16 Sb[32 * 136];
  __shared__ u16 RU[32 * 40];
  __shared__ float Ost[32 * 36];

  auto issue_kcv = [&](int c, int bf){
    long rowb = (long)b * CT + c * 32;
    #pragma unroll
    for (int p = 0; p < 2; p++){
      int X = p * 256 + tid; int r = X >> 4, jj = X & 15;
      gload16(kn + ((rowb + r) * 8 + h) * 128 + (jj ^ (r & 7)) * 8, &Kc[bf][(size_t)X * 8]);
    }
    if (lane < 32){
      int X = wv * 32 + lane; int r = X >> 2, jj = X & 3;
      gload16(vn + ((rowb + r) * 8 + h) * 256 + vs * 32 + (jj ^ swz3(r)) * 8, &Vs[bf][(size_t)X * 8]);
    }
    long sbase = ((long)bh * 64 + c) * 48;
    #pragma unroll
    for (int p = 0; p < 3; p++){
      int X = wv * 3 + p;
      if (lane == 0) gload16(scal_g + sbase + X * 4, &scal[bf][X * 4]);
    }
  };
  auto issue_rest = [&](int c){
    long rowb = (long)b * CT + c * 32;
    #pragma unroll
    for (int p = 0; p < 2; p++){
      int X = p * 256 + tid; int r = X >> 4, jj = X & 15;
      gload16(qn + ((rowb + r) * 8 + h) * 128 + (jj ^ (r & 7)) * 8, &Qc[(size_t)X * 8]);
    }
    long cb_ = (long)bh * 64 + c;
    const u16* Kb_ = KTS_g + cb_ * 4096;
    #pragma unroll
    for (int p = 0; p < 2; p++){
      int X = p * 256 + tid; int r = X >> 2, jj = X & 3;
      gload16(Kb_ + (r * 4 + (jj ^ swz3(r))) * 8, &KT[(size_t)X * 8]);
    }
    {
      int X = wv * 64 + lane;
      if (wv < 2){
        int r = X >> 2, jj = X & 3;
        gload16(Tinv_g + cb_ * 1024 + (r * 4 + (jj ^ swz3(r))) * 8, &Ti[(size_t)X * 8]);
      } else {
        int x2 = X - 128; int r = x2 >> 2, jj = x2 & 3;
        gload16(P_g + cb_ * 1024 + (r * 4 + (jj ^ swz3(r))) * 8, &Ps[(size_t)x2 * 8]);
      }
    }
  };

  // ---- prologue
  issue_kcv(0, 0);
  f32x4 st[4];
  {
    const float* pbv = prev + ((long)bh * 128) * 256 + vs * 32;
    #pragma unroll
    for (int tt = 0; tt < 4; tt++){
      int k = (nn * 4 + tt) * 16 + l15;
      #pragma unroll
      for (int j = 0; j < 4; j++){
        int v = mv * 16 + lhi * 4 + j;
        st[tt][j] = pbv[(long)k * 256 + v];
      }
    }
  }
  #pragma unroll
  for (int tt = 0; tt < 4; tt++){
    int k = (nn * 4 + tt) * 16 + l15;
    #pragma unroll
    for (int j = 0; j < 4; j++){
      int v = mv * 16 + lhi * 4 + j;
      Sb[v * 136 + k] = f2b(st[tt][j]);
    }
  }
  asm volatile("s_waitcnt lgkmcnt(0)" ::: "memory");
  __builtin_amdgcn_s_barrier();

  for (int c = 0; c < 64; ++c){
    int cb = c & 1;
    issue_rest(c);
    asm volatile("s_waitcnt vmcnt(5)" ::: "memory");
    __builtin_amdgcn_s_barrier();

    // ---- phase C: W = Gamma o (Sb^T Kc^T); R = V - W -> RU
    f32x4 wacc = {0.f,0.f,0.f,0.f};
    {
      int rv = mv * 16 + l15, rs = nn * 16 + l15;
      #pragma unroll
      for (int ks = 0; ks < 4; ks++){
        bf16x8 af = *(const bf16x8*)&Sb[rv * 136 + ks * 32 + lhi * 8];
        int slot = ks * 4 + lhi;
        bf16x8 bf_ = *(const bf16x8*)&Kc[cb][rs * 128 + (slot ^ (rs & 7)) * 8];
        wacc = __builtin_amdgcn_mfma_f32_16x16x32_bf16(af, bf_, wacc, 0, 0, 0);
      }
    }
    if (c + 1 < 64) issue_kcv(c + 1, cb ^ 1);
    {
      int s2 = nn * 16 + l15;
      float gs = scal[cb][s2];
      #pragma unroll
      for (int j = 0; j < 4; j++){
        int v = mv * 16 + lhi * 4 + j;
        float vv = b2f(Vs[cb][s2 * 32 + ((v >> 3) ^ swz3(s2)) * 8 + (v & 7)]);
        RU[v * 40 + s2] = f2b(vv - gs * wacc[j]);
      }
    }
    asm volatile("s_waitcnt lgkmcnt(0)" ::: "memory");
    if (c == 63) asm volatile("s_waitcnt vmcnt(0)" ::: "memory");
    else         asm volatile("s_waitcnt vmcnt(6)" ::: "memory");
    __builtin_amdgcn_s_barrier();

    // ---- phase E: U = Tinv @ R
    f32x4 uacc;
    {
      int rv = mv * 16 + l15, ri = nn * 16 + l15;
      bf16x8 aU = *(const bf16x8*)&RU[rv * 40 + lhi * 8];
      bf16x8 bT = *(const bf16x8*)&Ti[ri * 32 + (lhi ^ swz3(ri)) * 8];
      f32x4 z = {0.f,0.f,0.f,0.f};
      uacc = __builtin_amdgcn_mfma_f32_16x16x32_bf16(aU, bT, z, 0, 0, 0);
    }
    asm volatile("s_waitcnt lgkmcnt(0)" ::: "memory");
    __builtin_amdgcn_s_barrier();
    {
      int i_ = nn * 16 + l15;
      #pragma unroll
      for (int j = 0; j < 4; j++){
        int v = mv * 16 + lhi * 4 + j;
        RU[v * 40 + i_] = f2b(uacc[j]);
      }
    }
    asm volatile("s_waitcnt lgkmcnt(0)" ::: "memory");
    __builtin_amdgcn_s_barrier();

    // ---- phase F: O2 = U@P^T ; O1 = Sb^T Qc^T ; S' = Gtot*S + U@KTS^T
    f32x4 oacc, o1 = {0.f,0.f,0.f,0.f};
    float Gt = scal[cb][32];
    {
      int rv = mv * 16 + l15, ri = nn * 16 + l15;
      bf16x8 aU2 = *(const bf16x8*)&RU[rv * 40 + lhi * 8];
      bf16x8 bP = *(const bf16x8*)&Ps[ri * 32 + (lhi ^ swz3(ri)) * 8];
      f32x4 z = {0.f,0.f,0.f,0.f};
      oacc = __builtin_amdgcn_mfma_f32_16x16x32_bf16(aU2, bP, z, 0, 0, 0);
      #pragma unroll
      for (int ks = 0; ks < 4; ks++){
        bf16x8 aS = *(const bf16x8*)&Sb[rv * 136 + ks * 32 + lhi * 8];
        int slot = ks * 4 + lhi;
        bf16x8 bQ = *(const bf16x8*)&Qc[ri * 128 + (slot ^ (ri & 7)) * 8];
        o1 = __builtin_amdgcn_mfma_f32_16x16x32_bf16(aS, bQ, o1, 0, 0, 0);
      }
      #pragma unroll
      for (int tt = 0; tt < 4; tt++){
        int rk_ = (nn * 4 + tt) * 16 + l15;
        bf16x8 bK = *(const bf16x8*)&KT[rk_ * 32 + (lhi ^ swz3(rk_)) * 8];
        f32x4 ci = st[tt] * Gt;
        st[tt] = __builtin_amdgcn_mfma_f32_16x16x32_bf16(aU2, bK, ci, 0, 0, 0);
      }
    }
    asm volatile("s_waitcnt lgkmcnt(0)" ::: "memory");
    __builtin_amdgcn_s_barrier();

    // ---- phase G: write O to Ost, Sb-new; then coalesced obuf store
    {
      int i_ = nn * 16 + l15;
      float gi = scal[cb][i_];
      #pragma unroll
      for (int j = 0; j < 4; j++){
        int v = mv * 16 + lhi * 4 + j;
        Ost[i_ * 36 + v] = oacc[j] + gi * o1[j];
      }
      #pragma unroll
      for (int tt = 0; tt < 4; tt++){
        int k = (nn * 4 + tt) * 16 + l15;
        #pragma unroll
        for (int j = 0; j < 4; j++){
          int v = mv * 16 + lhi * 4 + j;
          Sb[v * 136 + k] = f2b(st[tt][j]);
        }
      }
    }
    asm volatile("s_waitcnt lgkmcnt(0)" ::: "memory");
    __builtin_amdgcn_s_barrier();
    {
      int r = tid >> 3, c4 = (tid & 7) * 4;
      float4 ov = *(const float4*)&Ost[r * 36 + c4];
      *(float4*)&obuf[(((long)bh * CT) + c * 32 + r) * 256 + vs * 32 + c4] = ov;
    }
  }

  // ---- epilogue: final state
  {
    float* fb = fstate + ((long)bh * 128) * 256 + vs * 32;
    #pragma unroll
    for (int tt = 0; tt < 4; tt++){
      int k = (nn * 4 + tt) * 16 + l15;
      #pragma unroll
      for (int j = 0; j < 4; j++){
        int v = mv * 16 + lhi * 4 + j;
        fb[(long)k * 256 + v] = st[tt][j];
      }
    }
  }
}

// ---------------- gated RMSNorm: one wave per (b,t,h) ----------------
// o is [b][h][t][256]; gate/ofin are [b][t][h*256]
__global__ __launch_bounds__(256) void rms_gate_k(
    const float* __restrict__ o, const u16* __restrict__ gate,
    const float* __restrict__ nw, u16* __restrict__ ofin)
{
  long idx = (long)blockIdx.x * 4 + (threadIdx.x >> 6);  // (b,t,h) linear
  int lane = threadIdx.x & 63;
  int h = (int)(idx & 7);
  long bt = idx >> 3;
  int b = (int)(bt >> 11);
  long t = bt & (CT - 1);
  long obase = (((long)(b * 8 + h)) * CT + t) * CDV + lane * 4;
  long base = idx * CDV + lane * 4;
  float4 ov = *(const float4*)(o + obase);
  float ss = ov.x*ov.x + ov.y*ov.y + ov.z*ov.z + ov.w*ov.w;
  #pragma unroll
  for (int off = 1; off < 64; off <<= 1) ss += __shfl_xor(ss, off);
  float r = rsqrtf(ss * (1.f / CDV) + 1e-5f);
  ushort4 g4 = *(const ushort4*)(gate + base);
  float w0 = nw[lane*4], w1 = nw[lane*4+1], w2 = nw[lane*4+2], w3 = nw[lane*4+3];
  ushort4 res;
  res.x = f2b(ov.x * r * w0 * sigm(b2f(g4.x)));
  res.y = f2b(ov.y * r * w1 * sigm(b2f(g4.y)));
  res.z = f2b(ov.z * r * w2 * sigm(b2f(g4.z)));
  res.w = f2b(ov.w * r * w3 * sigm(b2f(g4.w)));
  *(ushort4*)(ofin + base) = res;
}

// ---------------- host launch ----------------
extern "C" void kernel_launch(void* const* d_in, const int* in_sizes, int n_in,
                              void* d_out, int out_size, void* d_ws, size_t ws_size,
                              hipStream_t stream)
{
  (void)in_sizes; (void)n_in; (void)out_size; (void)ws_size;
  const float* X    = (const float*)d_in[0];
  const float* prev = (const float*)d_in[1];
  const float* Wq   = (const float*)d_in[2];
  const float* Wk   = (const float*)d_in[3];
  const float* Wv   = (const float*)d_in[4];
  const float* Wa   = (const float*)d_in[5];
  const float* Wb   = (const float*)d_in[6];
  const float* Wg   = (const float*)d_in[7];
  const float* Wo   = (const float*)d_in[8];
  const float* qcw  = (const float*)d_in[9];
  const float* qcb  = (const float*)d_in[10];
  const float* kcw  = (const float*)d_in[11];
  const float* kcb  = (const float*)d_in[12];
  const float* vcw  = (const float*)d_in[13];
  const float* vcb  = (const float*)d_in[14];
  const float* onw  = (const float*)d_in[15];
  const float* Alog = (const float*)d_in[16];
  const float* dtb  = (const float*)d_in[17];

  float* out = (float*)d_out;
  float* fstate = out + (long)CB * CT * CD;

  char* ws = (char*)d_ws;
  size_t off = 0;
  auto alloc = [&](size_t bytes) -> char* {
    char* p = ws + off;
    off += (bytes + 255) & ~(size_t)255;
    return p;
  };
  u16* Xb   = (u16*)alloc(NROW * CD * 2);
  u16* Wqt  = (u16*)alloc((size_t)1024 * 1024 * 2);
  u16* Wkt  = (u16*)alloc((size_t)1024 * 1024 * 2);
  u16* Wvt  = (u16*)alloc((size_t)2048 * 1024 * 2);
  u16* Wgt  = (u16*)alloc((size_t)2048 * 1024 * 2);
  u16* Wot  = (u16*)alloc((size_t)1024 * 2048 * 2);
  u16* qpre = (u16*)alloc(NROW * 1024 * 2);
  u16* kpre = (u16*)alloc(NROW * 1024 * 2);
  u16* vpre = (u16*)alloc(NROW * 2048 * 2);
  u16* gpre = (u16*)alloc(NROW * 2048 * 2);
  float* alpha = (float*)alloc(NROW * 8 * 4);
  float* beta  = (float*)alloc(NROW * 8 * 4);
  u16* qn   = (u16*)alloc(NROW * 1024 * 2);
  u16* kn   = (u16*)alloc(NROW * 1024 * 2);
  u16* vn   = (u16*)alloc(NROW * 2048 * 2);
  u16* ofin = (u16*)alloc(NROW * 2048 * 2);
  u16* Wab  = (u16*)alloc((size_t)16 * 1024 * 2);
  // o (B,H,T,DV) f32 = 67MB reuses the dead qpre+kpre+vpre region (exactly 67MB)
  float* obuf = (float*)qpre;
  // chunk metadata aliases: KTS -> Xb (16.78MB exact); Tinv/P/scal -> Wqt..Wgt (12MB)
  u16* KTS_g  = Xb;
  u16* Tinv_g = Wqt;
  u16* P_g    = Tinv_g + (size_t)2048 * 1024;
  float* scal_g = (float*)(P_g + (size_t)2048 * 1024);

  cast_f32_bf16_k<<<2048, 256, 0, stream>>>(X, Xb, NROW * CD / 4);
  build_wab_k<<<64, 256, 0, stream>>>(Wa, Wb, Wab);
  transpose_cast_k<<<dim3(32, 32), 256, 0, stream>>>(Wq, Wqt, 1024, 1024);
  transpose_cast_k<<<dim3(32, 32), 256, 0, stream>>>(Wk, Wkt, 1024, 1024);
  transpose_cast_k<<<dim3(64, 32), 256, 0, stream>>>(Wv, Wvt, 1024, 2048);
  transpose_cast_k<<<dim3(64, 32), 256, 0, stream>>>(Wg, Wgt, 1024, 2048);
  transpose_cast_k<<<dim3(32, 64), 256, 0, stream>>>(Wo, Wot, 2048, 1024);

  gemm_nt<u16><<<dim3(8, 64), 256, 0, stream>>>(Xb, Wqt, qpre, 8192, 1024, 1024);
  gemm_nt<u16><<<dim3(8, 64), 256, 0, stream>>>(Xb, Wkt, kpre, 8192, 1024, 1024);
  gemm_nt<u16><<<dim3(16, 64), 256, 0, stream>>>(Xb, Wvt, vpre, 8192, 2048, 1024);
  gemm_nt<u16><<<dim3(16, 64), 256, 0, stream>>>(Xb, Wgt, gpre, 8192, 2048, 1024);
  ab_mfma_k<<<128, 256, 0, stream>>>(Xb, Wab, Alog, dtb, alpha, beta);

  conv_silu_k<128, true><<<CB * CT * CH, 128, 0, stream>>>(qpre, qcw, qcb, qn);
  conv_silu_k<128, true><<<CB * CT * CH, 128, 0, stream>>>(kpre, kcw, kcb, kn);
  conv_silu_k<256, false><<<CB * CT * CH, 256, 0, stream>>>(vpre, vcw, vcb, vn);

  chunk_meta_k<<<2048, 256, 0, stream>>>(qn, kn, alpha, beta, Tinv_g, P_g, KTS_g, scal_g);
  chunk_scan_k<<<256, 256, 0, stream>>>(qn, kn, vn, Tinv_g, P_g, KTS_g, scal_g,
                                        prev, obuf, fstate);

  rms_gate_k<<<CB * CT * CH / 4, 256, 0, stream>>>(obuf, gpre, onw, ofin);
  gemm_nt<float><<<dim3(8, 64), 256, 0, stream>>>(ofin, Wot, out, 8192, 1024, 2048);
}